// Round 1
// baseline (1136.447 us; speedup 1.0000x reference)
//
#include <hip/hip_runtime.h>
#include <math.h>

// Problem constants
#define DM 1024      // d_model
#define LL 2048      // sequence length
#define BB 4         // batch
#define HH 16        // heads
#define HD 64        // head dim
#define CC 64        // chunk size for linear attention
#define NC (LL / CC) // 32 chunks per sequence
#define EPSC 1e-6f

__device__ __forceinline__ float featf(float x) {
    // elu(x) + 1
    return x > 0.f ? x + 1.f : __expf(x);
}

// ---------------------------------------------------------------------------
// GEMM: Y[M=8192 x 1024] = X @ W + bias, optional elu+1 activation.
// 128x128 tile, BK=8, 256 threads, 8x8 per thread, register prefetch.
// ---------------------------------------------------------------------------
__global__ __launch_bounds__(256) void gemm_bias_act(
    const float* __restrict__ X, const float* __restrict__ W,
    const float* __restrict__ bias, float* __restrict__ Y, int act)
{
    __shared__ float As[8][128];  // As[kk][m]
    __shared__ float Bs[8][128];  // Bs[kk][n]

    const int tid = threadIdx.x;
    const int tx = tid & 15;        // 0..15 -> col groups
    const int ty = tid >> 4;        // 0..15 -> row groups
    const int m0 = blockIdx.y * 128;
    const int n0 = blockIdx.x * 128;

    const int arow = tid >> 1;          // 0..127
    const int akc  = (tid & 1) * 4;     // 0 or 4
    const int brow = tid >> 5;          // 0..7
    const int bcol = (tid & 31) * 4;    // 0..124

    float acc[8][8];
#pragma unroll
    for (int r = 0; r < 8; ++r)
#pragma unroll
        for (int c = 0; c < 8; ++c) acc[r][c] = 0.f;

    // prefetch first tile
    float4 av = *(const float4*)(X + (m0 + arow) * DM + akc);
    float4 bv = *(const float4*)(W + brow * DM + n0 + bcol);

    for (int k0 = 0; k0 < DM; k0 += 8) {
        As[akc + 0][arow] = av.x;
        As[akc + 1][arow] = av.y;
        As[akc + 2][arow] = av.z;
        As[akc + 3][arow] = av.w;
        *(float4*)&Bs[brow][bcol] = bv;
        __syncthreads();

        if (k0 + 8 < DM) {
            av = *(const float4*)(X + (m0 + arow) * DM + (k0 + 8) + akc);
            bv = *(const float4*)(W + (k0 + 8 + brow) * DM + n0 + bcol);
        }

#pragma unroll
        for (int kk = 0; kk < 8; ++kk) {
            float4 a0 = *(const float4*)&As[kk][ty * 4];
            float4 a1 = *(const float4*)&As[kk][64 + ty * 4];
            float4 b0 = *(const float4*)&Bs[kk][tx * 4];
            float4 b1 = *(const float4*)&Bs[kk][64 + tx * 4];
            float a[8] = {a0.x, a0.y, a0.z, a0.w, a1.x, a1.y, a1.z, a1.w};
            float b[8] = {b0.x, b0.y, b0.z, b0.w, b1.x, b1.y, b1.z, b1.w};
#pragma unroll
            for (int r = 0; r < 8; ++r)
#pragma unroll
                for (int c = 0; c < 8; ++c)
                    acc[r][c] = fmaf(a[r], b[c], acc[r][c]);
        }
        __syncthreads();
    }

    // epilogue: bias + optional activation, float4 stores
#pragma unroll
    for (int r = 0; r < 8; ++r) {
        const int row = m0 + ((r < 4) ? (ty * 4 + r) : (64 + ty * 4 + (r - 4)));
#pragma unroll
        for (int cg = 0; cg < 2; ++cg) {
            const int col = n0 + ((cg == 0) ? (tx * 4) : (64 + tx * 4));
            float4 o;
            o.x = acc[r][cg * 4 + 0] + bias[col + 0];
            o.y = acc[r][cg * 4 + 1] + bias[col + 1];
            o.z = acc[r][cg * 4 + 2] + bias[col + 2];
            o.w = acc[r][cg * 4 + 3] + bias[col + 3];
            if (act) {
                o.x = featf(o.x); o.y = featf(o.y);
                o.z = featf(o.z); o.w = featf(o.w);
            }
            *(float4*)(Y + row * DM + col) = o;
        }
    }
}

// ---------------------------------------------------------------------------
// Phase A: per-chunk state M_c[dv][j] = sum_{t in chunk} v_t[dv] * k_t[j]
//          and per-chunk column sums Zc[j] = sum_t k_t[j].
// One block per (b,h,chunk). blk = bh*NC + c.
// ---------------------------------------------------------------------------
__global__ __launch_bounds__(256) void chunk_state(
    const float* __restrict__ Kf, const float* __restrict__ Vf,
    float* __restrict__ Mstates, float* __restrict__ Zc)
{
    __shared__ float Ks[CC * 64];
    __shared__ float Vs[CC * 64];
    const int blk = blockIdx.x;
    const int bh = blk / NC, c = blk % NC;
    const int b = bh / HH, h = bh % HH;
    const int tid = threadIdx.x;
    const size_t gbase = ((size_t)(b * LL + c * CC)) * DM + h * HD;

#pragma unroll
    for (int e = 0; e < 16; ++e) {
        const int idx = e * 256 + tid;
        const int t = idx >> 6, j = idx & 63;
        Ks[idx] = Kf[gbase + t * DM + j];
        Vs[idx] = Vf[gbase + t * DM + j];
    }
    __syncthreads();

    float* Mout = Mstates + (size_t)blk * 4096;
#pragma unroll
    for (int e = 0; e < 16; ++e) {
        const int idx = e * 256 + tid;
        const int dv = idx >> 6, j = idx & 63;
        float acc = 0.f;
        for (int t = 0; t < CC; ++t)
            acc = fmaf(Vs[t * 64 + dv], Ks[t * 64 + j], acc);
        Mout[idx] = acc;
    }
    if (tid < 64) {
        float z = 0.f;
        for (int t = 0; t < CC; ++t) z += Ks[t * 64 + tid];
        Zc[(size_t)blk * 64 + tid] = z;
    }
}

// ---------------------------------------------------------------------------
// Phase B: in-place exclusive prefix over chunks (per bh) for M and Z.
// One block per bh.
// ---------------------------------------------------------------------------
__global__ __launch_bounds__(256) void prefix_state(
    float* __restrict__ Mstates, float* __restrict__ Zc)
{
    const int bh = blockIdx.x;
    const int tid = threadIdx.x;
    float run[16];
#pragma unroll
    for (int e = 0; e < 16; ++e) run[e] = 0.f;

    for (int c = 0; c < NC; ++c) {
        float* p = Mstates + ((size_t)bh * NC + c) * 4096;
#pragma unroll
        for (int e = 0; e < 16; ++e) {
            const int idx = e * 256 + tid;
            const float v = p[idx];
            p[idx] = run[e];
            run[e] += v;
        }
    }
    if (tid < 64) {
        float z = 0.f;
        for (int c = 0; c < NC; ++c) {
            float* q = Zc + ((size_t)bh * NC + c) * 64;
            const float v = q[tid];
            q[tid] = z;
            z += v;
        }
    }
}

// ---------------------------------------------------------------------------
// Phase C: per-chunk output.
//   A[i][t] = q_i . v_t  (t <= i used)
//   out[i][j] = (Q_c @ Mprev + tril(A) @ K_c)[i][j] / (q_i[j]*Z_i[j] + eps)
// One block per (b,h,chunk). 64 KiB LDS. Wave w handles rows i = e*4+w.
// V tile stored rotate-swizzled: VM[t*64 + ((col+t)&63)] to avoid stride-64
// bank conflicts in the A-compute stage; VM is reused for Mprev afterwards.
// ---------------------------------------------------------------------------
__global__ __launch_bounds__(256) void chunk_attn(
    const float* __restrict__ Qf, const float* __restrict__ Kf,
    const float* __restrict__ Vf, const float* __restrict__ Mprev,
    const float* __restrict__ Zprev, float* __restrict__ Out)
{
    __shared__ float Qs[4096];
    __shared__ float Ks[4096];
    __shared__ float VM[4096];
    __shared__ float As[4096];

    const int blk = blockIdx.x;
    const int bh = blk / NC, c = blk % NC;
    const int b = bh / HH, h = bh % HH;
    const int tid = threadIdx.x;
    const int w = tid >> 6, lane = tid & 63;
    const size_t gbase = ((size_t)(b * LL + c * CC)) * DM + h * HD;

#pragma unroll
    for (int e = 0; e < 16; ++e) {
        const int idx = e * 256 + tid;
        const int t = idx >> 6, col = idx & 63;
        Qs[idx] = Qf[gbase + t * DM + col];
        Ks[idx] = Kf[gbase + t * DM + col];
        VM[t * 64 + ((col + t) & 63)] = Vf[gbase + t * DM + col];
    }
    __syncthreads();

    // Stage 1: A[i][t] = q_i . v_t  (compute full matrix; t>i never read)
#pragma unroll 4
    for (int e = 0; e < 16; ++e) {
        const int i = e * 4 + w;
        const int t = lane;
        float acc = 0.f;
        for (int dv = 0; dv < 64; ++dv)
            acc = fmaf(Qs[i * 64 + dv], VM[t * 64 + ((dv + t) & 63)], acc);
        As[i * 64 + t] = acc;
    }
    __syncthreads();

    // Overwrite VM with Mprev (straight layout M[dv][j])
    const float* Mp = Mprev + (size_t)blk * 4096;
#pragma unroll
    for (int e = 0; e < 16; ++e) {
        const int idx = e * 256 + tid;
        VM[idx] = Mp[idx];
    }
    const float zp = Zprev[(size_t)blk * 64 + lane];
    __syncthreads();

    // Stage 2: inter + intra + elementwise denominator
#pragma unroll 4
    for (int e = 0; e < 16; ++e) {
        const int i = e * 4 + w;
        const int j = lane;
        float inter = 0.f;
        for (int dv = 0; dv < 64; ++dv)
            inter = fmaf(Qs[i * 64 + dv], VM[dv * 64 + j], inter);
        float intra = 0.f, z = zp;
        for (int t = 0; t <= i; ++t) {
            intra = fmaf(As[i * 64 + t], Ks[t * 64 + j], intra);
            z += Ks[t * 64 + j];
        }
        const float denom = fmaf(Qs[i * 64 + j], z, EPSC);
        Out[gbase + i * DM + j] = (inter + intra) / denom;
    }
}

// ---------------------------------------------------------------------------
// Launch
// ---------------------------------------------------------------------------
extern "C" void kernel_launch(void* const* d_in, const int* in_sizes, int n_in,
                              void* d_out, int out_size, void* d_ws, size_t ws_size,
                              hipStream_t stream)
{
    (void)in_sizes; (void)n_in; (void)out_size; (void)ws_size;

    const float* queries = (const float*)d_in[0];
    const float* keys    = (const float*)d_in[1];
    const float* values  = (const float*)d_in[2];
    const float* Wq = (const float*)d_in[3];
    const float* bq = (const float*)d_in[4];
    const float* Wk = (const float*)d_in[5];
    const float* bk = (const float*)d_in[6];
    const float* Wv = (const float*)d_in[7];
    const float* bv = (const float*)d_in[8];
    const float* Wo = (const float*)d_in[9];
    const float* bo = (const float*)d_in[10];

    char* ws = (char*)d_ws;
    const size_t SZ = (size_t)BB * LL * DM * sizeof(float);  // 32 MiB
    float* Q    = (float*)(ws);
    float* Kl   = (float*)(ws + SZ);
    float* Vp   = (float*)(ws + 2 * SZ);
    float* attn = (float*)(ws + 3 * SZ);
    float* Mst  = (float*)(ws + 4 * SZ);                       // 32 MiB (64*32*4096*4)
    float* Zc   = (float*)(ws + 5 * SZ);                       // 512 KiB

    const dim3 gblk(256);
    const dim3 ggemm(DM / 128, (BB * LL) / 128);  // (8, 64)

    gemm_bias_act<<<ggemm, gblk, 0, stream>>>(queries, Wq, bq, Q, 1);
    gemm_bias_act<<<ggemm, gblk, 0, stream>>>(keys,    Wk, bk, Kl, 1);
    gemm_bias_act<<<ggemm, gblk, 0, stream>>>(values,  Wv, bv, Vp, 0);

    chunk_state<<<dim3(BB * HH * NC), gblk, 0, stream>>>(Kl, Vp, Mst, Zc);
    prefix_state<<<dim3(BB * HH), gblk, 0, stream>>>(Mst, Zc);
    chunk_attn<<<dim3(BB * HH * NC), gblk, 0, stream>>>(Q, Kl, Vp, Mst, Zc, attn);

    gemm_bias_act<<<ggemm, gblk, 0, stream>>>(attn, Wo, bo, (float*)d_out, 0);
}

// Round 2
// 528.371 us; speedup vs baseline: 2.1508x; 2.1508x over previous
//
#include <hip/hip_runtime.h>
#include <math.h>

// Problem constants
#define DM 1024      // d_model
#define LL 2048      // sequence length
#define BB 4         // batch
#define HH 16        // heads
#define HD 64        // head dim
#define CC 64        // chunk size for linear attention
#define NC (LL / CC) // 32 chunks per sequence
#define EPSC 1e-6f

typedef __attribute__((ext_vector_type(8))) short short8;   // 8 bf16 (4 VGPRs)
typedef __attribute__((ext_vector_type(4))) float floatx4;  // MFMA accumulator

__device__ __forceinline__ float featf(float x) {
    // elu(x) + 1
    return x > 0.f ? x + 1.f : __expf(x);
}

// round-to-nearest-even f32 -> bf16 bits
__device__ __forceinline__ unsigned short f2bf(float f) {
    unsigned int u = __builtin_bit_cast(unsigned int, f);
    u = (u + 0x7FFFu + ((u >> 16) & 1u)) >> 16;
    return (unsigned short)u;
}

__device__ __forceinline__ void gload_lds16(const void* g, void* l) {
    __builtin_amdgcn_global_load_lds(
        (const __attribute__((address_space(1))) void*)g,
        (__attribute__((address_space(3))) void*)l,
        16, 0, 0);
}

// ---------------------------------------------------------------------------
// f32 -> bf16 elementwise convert. Each thread: 8 floats -> 8 bf16 (16B store).
// ---------------------------------------------------------------------------
__global__ __launch_bounds__(256) void convert_bf16(
    const float* __restrict__ in, unsigned short* __restrict__ out)
{
    const int i = blockIdx.x * 256 + threadIdx.x;  // covers 8 elements
    const float4 a = ((const float4*)in)[i * 2];
    const float4 b = ((const float4*)in)[i * 2 + 1];
    union { unsigned short s[8]; uint4 v; } o;
    o.s[0] = f2bf(a.x); o.s[1] = f2bf(a.y); o.s[2] = f2bf(a.z); o.s[3] = f2bf(a.w);
    o.s[4] = f2bf(b.x); o.s[5] = f2bf(b.y); o.s[6] = f2bf(b.z); o.s[7] = f2bf(b.w);
    ((uint4*)out)[i] = o.v;
}

// ---------------------------------------------------------------------------
// W [K=1024][N=1024] f32 -> Wt [N][K] bf16 (transpose + convert). 64x64 tiles.
// ---------------------------------------------------------------------------
__global__ __launch_bounds__(256) void transpose_conv(
    const float* __restrict__ W, unsigned short* __restrict__ Wt)
{
    __shared__ float tile[64][65];
    const int r0 = blockIdx.y * 64, c0 = blockIdx.x * 64;
    const int tid = threadIdx.x;
#pragma unroll
    for (int e = 0; e < 16; ++e) {
        const int idx = e * 256 + tid;
        const int r = idx >> 6, c = idx & 63;
        tile[r][c] = W[(size_t)(r0 + r) * DM + c0 + c];
    }
    __syncthreads();
#pragma unroll
    for (int e = 0; e < 16; ++e) {
        const int idx = e * 256 + tid;
        const int co = idx >> 6, ro = idx & 63;
        Wt[(size_t)(c0 + co) * DM + r0 + ro] = f2bf(tile[ro][co]);
    }
}

// ---------------------------------------------------------------------------
// bf16 MFMA GEMM: Y[M x 1024] = X @ W + bias (+ optional elu+1), f32 out.
// X: [M][1024] bf16 row-major. Wt: [1024][1024] bf16 = W^T, i.e. Wt[n][k].
// 128x128 tile, BK=32, 4 waves each computing 64x64 via 4x4 of 16x16x32 MFMA.
// Staging via global_load_lds width 16; per-row XOR-4 k-chunk swizzle cuts
// ds_read_b128 fragment-read bank conflicts 8-way -> 4-way.
// ---------------------------------------------------------------------------
__global__ __launch_bounds__(256) void gemm_mfma(
    const unsigned short* __restrict__ X,
    const unsigned short* __restrict__ Wt,
    const float* __restrict__ bias,
    float* __restrict__ Y, int act)
{
    __shared__ __align__(16) unsigned short As[128 * 32];  // [m][kchunk swizzled]
    __shared__ __align__(16) unsigned short Bs[128 * 32];  // [n][kchunk swizzled]

    const int tid = threadIdx.x;
    const int lane = tid & 63;
    const int w = tid >> 6;          // wave 0..3
    const int wr = w >> 1, wc = w & 1;
    const int fm = lane & 15;        // row (A) / col (B) within 16-tile
    const int fq = lane >> 4;        // k-quad 0..3 (8 bf16 each)
    const int m0 = blockIdx.y * 128, n0 = blockIdx.x * 128;

    floatx4 acc[4][4];
#pragma unroll
    for (int i = 0; i < 4; ++i)
#pragma unroll
        for (int j = 0; j < 4; ++j) acc[i][j] = (floatx4){0.f, 0.f, 0.f, 0.f};

    // staging coords: LDS chunk idx holds global k-chunk (idx&3)^(row&3)
    const int row0 = tid >> 2;
    const int row1 = row0 + 64;
    const int slot0 = (tid & 3) ^ (row0 & 3);
    const int slot1 = (tid & 3) ^ (row1 & 3);
    const unsigned short* Xa = X + (size_t)(m0 + row0) * DM + slot0 * 8;
    const unsigned short* Xb = X + (size_t)(m0 + row1) * DM + slot1 * 8;
    const unsigned short* Wa = Wt + (size_t)(n0 + row0) * DM + slot0 * 8;
    const unsigned short* Wb = Wt + (size_t)(n0 + row1) * DM + slot1 * 8;

    const int fswz = ((fq ^ (fm & 3)) << 3);  // fragment k-chunk after swizzle

    for (int k0 = 0; k0 < DM; k0 += 32) {
        gload_lds16(Xa + k0, As + (size_t)tid * 8);
        gload_lds16(Xb + k0, As + (size_t)(256 + tid) * 8);
        gload_lds16(Wa + k0, Bs + (size_t)tid * 8);
        gload_lds16(Wb + k0, Bs + (size_t)(256 + tid) * 8);
        __syncthreads();  // drains vmcnt before barrier

        short8 af[4], bf[4];
#pragma unroll
        for (int mt = 0; mt < 4; ++mt) {
            const int r = wr * 64 + mt * 16 + fm;
            af[mt] = *(const short8*)(As + r * 32 + fswz);
        }
#pragma unroll
        for (int nt = 0; nt < 4; ++nt) {
            const int r = wc * 64 + nt * 16 + fm;
            bf[nt] = *(const short8*)(Bs + r * 32 + fswz);
        }
#pragma unroll
        for (int mt = 0; mt < 4; ++mt)
#pragma unroll
            for (int nt = 0; nt < 4; ++nt)
                acc[mt][nt] = __builtin_amdgcn_mfma_f32_16x16x32_bf16(
                    af[mt], bf[nt], acc[mt][nt], 0, 0, 0);
        __syncthreads();  // protect LDS reuse
    }

    // epilogue: C/D layout col=lane&15, row=quad*4+reg (m89-verified)
#pragma unroll
    for (int nt = 0; nt < 4; ++nt) {
        const int col = n0 + wc * 64 + nt * 16 + fm;
        const float bv = bias[col];
#pragma unroll
        for (int mt = 0; mt < 4; ++mt) {
            const int rbase = m0 + wr * 64 + mt * 16 + fq * 4;
#pragma unroll
            for (int r = 0; r < 4; ++r) {
                float v = acc[mt][nt][r] + bv;
                if (act) v = featf(v);
                Y[(size_t)(rbase + r) * DM + col] = v;
            }
        }
    }
}

// ---------------------------------------------------------------------------
// Phase A: per-chunk state M_c[dv][j] = sum_{t in chunk} v_t[dv] * k_t[j]
//          and per-chunk column sums Zc[j] = sum_t k_t[j].
// ---------------------------------------------------------------------------
__global__ __launch_bounds__(256) void chunk_state(
    const float* __restrict__ Kf, const float* __restrict__ Vf,
    float* __restrict__ Mstates, float* __restrict__ Zc)
{
    __shared__ float Ks[CC * 64];
    __shared__ float Vs[CC * 64];
    const int blk = blockIdx.x;
    const int bh = blk / NC, c = blk % NC;
    const int b = bh / HH, h = bh % HH;
    const int tid = threadIdx.x;
    const size_t gbase = ((size_t)(b * LL + c * CC)) * DM + h * HD;

#pragma unroll
    for (int e = 0; e < 16; ++e) {
        const int idx = e * 256 + tid;
        const int t = idx >> 6, j = idx & 63;
        Ks[idx] = Kf[gbase + t * DM + j];
        Vs[idx] = Vf[gbase + t * DM + j];
    }
    __syncthreads();

    float* Mout = Mstates + (size_t)blk * 4096;
#pragma unroll
    for (int e = 0; e < 16; ++e) {
        const int idx = e * 256 + tid;
        const int dv = idx >> 6, j = idx & 63;
        float acc = 0.f;
        for (int t = 0; t < CC; ++t)
            acc = fmaf(Vs[t * 64 + dv], Ks[t * 64 + j], acc);
        Mout[idx] = acc;
    }
    if (tid < 64) {
        float z = 0.f;
        for (int t = 0; t < CC; ++t) z += Ks[t * 64 + tid];
        Zc[(size_t)blk * 64 + tid] = z;
    }
}

// ---------------------------------------------------------------------------
// Phase B: in-place exclusive prefix over chunks, parallel over elements.
// grid = BB*HH*16; block (bh, slice) handles 256 elements of the 4096 state.
// ---------------------------------------------------------------------------
__global__ __launch_bounds__(256) void prefix_state(
    float* __restrict__ Mstates, float* __restrict__ Zc)
{
    const int bh = blockIdx.x >> 4;
    const int slice = blockIdx.x & 15;
    const int off = slice * 256 + threadIdx.x;
    float run = 0.f;
    float* base = Mstates + (size_t)bh * NC * 4096 + off;
    for (int c = 0; c < NC; ++c) {
        const float v = base[(size_t)c * 4096];
        base[(size_t)c * 4096] = run;
        run += v;
    }
    if (slice == 0 && threadIdx.x < 64) {
        float z = 0.f;
        float* zb = Zc + (size_t)bh * NC * 64 + threadIdx.x;
        for (int c = 0; c < NC; ++c) {
            const float v = zb[c * 64];
            zb[c * 64] = z;
            z += v;
        }
    }
}

// ---------------------------------------------------------------------------
// Phase C: per-chunk output -> bf16.
//   A[i][t] = q_i . v_t  (t <= i used)
//   out[i][j] = (Q_c @ Mprev + tril(A) @ K_c)[i][j] / (q_i[j]*Z_i[j] + eps)
// ---------------------------------------------------------------------------
__global__ __launch_bounds__(256) void chunk_attn(
    const float* __restrict__ Qf, const float* __restrict__ Kf,
    const float* __restrict__ Vf, const float* __restrict__ Mprev,
    const float* __restrict__ Zprev, unsigned short* __restrict__ Outb)
{
    __shared__ float Qs[4096];
    __shared__ float Ks[4096];
    __shared__ float VM[4096];
    __shared__ float As[4096];

    const int blk = blockIdx.x;
    const int bh = blk / NC, c = blk % NC;
    const int b = bh / HH, h = bh % HH;
    const int tid = threadIdx.x;
    const int w = tid >> 6, lane = tid & 63;
    const size_t gbase = ((size_t)(b * LL + c * CC)) * DM + h * HD;

#pragma unroll
    for (int e = 0; e < 16; ++e) {
        const int idx = e * 256 + tid;
        const int t = idx >> 6, col = idx & 63;
        Qs[idx] = Qf[gbase + t * DM + col];
        Ks[idx] = Kf[gbase + t * DM + col];
        VM[t * 64 + ((col + t) & 63)] = Vf[gbase + t * DM + col];  // rotate-swizzled
    }
    __syncthreads();

    // Stage 1: A[i][t] = q_i . v_t
#pragma unroll 4
    for (int e = 0; e < 16; ++e) {
        const int i = e * 4 + w;
        const int t = lane;
        float acc = 0.f;
        for (int dv = 0; dv < 64; ++dv)
            acc = fmaf(Qs[i * 64 + dv], VM[t * 64 + ((dv + t) & 63)], acc);
        As[i * 64 + t] = acc;
    }
    __syncthreads();

    // Overwrite VM with Mprev (straight layout M[dv][j])
    const float* Mp = Mprev + (size_t)blk * 4096;
#pragma unroll
    for (int e = 0; e < 16; ++e) {
        const int idx = e * 256 + tid;
        VM[idx] = Mp[idx];
    }
    const float zp = Zprev[(size_t)blk * 64 + lane];
    __syncthreads();

    // Stage 2: inter + intra + elementwise denominator
#pragma unroll 4
    for (int e = 0; e < 16; ++e) {
        const int i = e * 4 + w;
        const int j = lane;
        float inter = 0.f;
        for (int dv = 0; dv < 64; ++dv)
            inter = fmaf(Qs[i * 64 + dv], VM[dv * 64 + j], inter);
        float intra = 0.f, z = zp;
        for (int t = 0; t <= i; ++t) {
            intra = fmaf(As[i * 64 + t], Ks[t * 64 + j], intra);
            z += Ks[t * 64 + j];
        }
        const float denom = fmaf(Qs[i * 64 + j], z, EPSC);
        Outb[gbase + i * DM + j] = f2bf((inter + intra) / denom);
    }
}

// ---------------------------------------------------------------------------
// Launch
// ---------------------------------------------------------------------------
extern "C" void kernel_launch(void* const* d_in, const int* in_sizes, int n_in,
                              void* d_out, int out_size, void* d_ws, size_t ws_size,
                              hipStream_t stream)
{
    (void)in_sizes; (void)n_in; (void)out_size; (void)ws_size;

    const float* queries = (const float*)d_in[0];
    const float* keys    = (const float*)d_in[1];
    const float* values  = (const float*)d_in[2];
    const float* Wq = (const float*)d_in[3];
    const float* bq = (const float*)d_in[4];
    const float* Wk = (const float*)d_in[5];
    const float* bk = (const float*)d_in[6];
    const float* Wv = (const float*)d_in[7];
    const float* bv = (const float*)d_in[8];
    const float* Wo = (const float*)d_in[9];
    const float* bo = (const float*)d_in[10];

    char* ws = (char*)d_ws;
    const size_t MB = 1u << 20;
    // bf16 input buffers (dead after their GEMM -> reused)
    unsigned short* qb  = (unsigned short*)(ws);             // 16 MB
    unsigned short* kb  = (unsigned short*)(ws + 16 * MB);   // 16 MB
    unsigned short* vb  = (unsigned short*)(ws + 32 * MB);   // 16 MB
    unsigned short* Wqt = (unsigned short*)(ws + 48 * MB);   // 2 MB each
    unsigned short* Wkt = (unsigned short*)(ws + 50 * MB);
    unsigned short* Wvt = (unsigned short*)(ws + 52 * MB);
    unsigned short* Wot = (unsigned short*)(ws + 54 * MB);
    float* Qf = (float*)(ws + 56 * MB);                      // 32 MB
    float* Kf = (float*)(ws + 88 * MB);                      // 32 MB
    float* Vf = (float*)(ws + 120 * MB);                     // 32 MB
    float* Zc = (float*)(ws + 152 * MB);                     // 0.5 MB
    // reuse: qb -> attn bf16 (16 MB); kb+vb -> Mst (32 MB)
    unsigned short* attnb = (unsigned short*)(ws);
    float* Mst = (float*)(ws + 16 * MB);

    const dim3 gblk(256);
    const int NCONV = (BB * LL * DM) / (8 * 256);            // 4096 blocks
    const dim3 gT(16, 16);
    const dim3 gG(DM / 128, (BB * LL) / 128);                // (8, 64)

    convert_bf16<<<dim3(NCONV), gblk, 0, stream>>>(queries, qb);
    convert_bf16<<<dim3(NCONV), gblk, 0, stream>>>(keys, kb);
    convert_bf16<<<dim3(NCONV), gblk, 0, stream>>>(values, vb);
    transpose_conv<<<gT, gblk, 0, stream>>>(Wq, Wqt);
    transpose_conv<<<gT, gblk, 0, stream>>>(Wk, Wkt);
    transpose_conv<<<gT, gblk, 0, stream>>>(Wv, Wvt);
    transpose_conv<<<gT, gblk, 0, stream>>>(Wo, Wot);

    gemm_mfma<<<gG, gblk, 0, stream>>>(qb, Wqt, bq, Qf, 1);
    gemm_mfma<<<gG, gblk, 0, stream>>>(kb, Wkt, bk, Kf, 1);
    gemm_mfma<<<gG, gblk, 0, stream>>>(vb, Wvt, bv, Vf, 0);

    chunk_state<<<dim3(BB * HH * NC), gblk, 0, stream>>>(Kf, Vf, Mst, Zc);
    prefix_state<<<dim3(BB * HH * 16), gblk, 0, stream>>>(Mst, Zc);
    chunk_attn<<<dim3(BB * HH * NC), gblk, 0, stream>>>(Qf, Kf, Vf, Mst, Zc, attnb);

    gemm_mfma<<<gG, gblk, 0, stream>>>(attnb, Wot, bo, (float*)d_out, 0);
}

// Round 3
// 369.553 us; speedup vs baseline: 3.0752x; 1.4298x over previous
//
#include <hip/hip_runtime.h>
#include <math.h>

// Problem constants
#define DM 1024      // d_model
#define LL 2048      // sequence length
#define BB 4         // batch
#define HH 16        // heads
#define HD 64        // head dim
#define CC 64        // chunk size
#define NC (LL / CC) // 32 chunks
#define EPSC 1e-6f
#define PS 72        // padded LDS stride (shorts) for 64-wide bf16 tiles

typedef __attribute__((ext_vector_type(8))) short short8;   // 8 bf16 (4 VGPRs)
typedef __attribute__((ext_vector_type(4))) float floatx4;  // MFMA accumulator

__device__ __forceinline__ float featf(float x) { return x > 0.f ? x + 1.f : __expf(x); }

// round-to-nearest-even f32 -> bf16 bits
__device__ __forceinline__ unsigned short f2bf(float f) {
    unsigned int u = __builtin_bit_cast(unsigned int, f);
    u = (u + 0x7FFFu + ((u >> 16) & 1u)) >> 16;
    return (unsigned short)u;
}
__device__ __forceinline__ float bf2f(unsigned short h) {
    return __builtin_bit_cast(float, (unsigned int)h << 16);
}
// split f32 into bf16 hi + bf16 lo (f ~= hi + lo, ~1e-4 rel accuracy)
__device__ __forceinline__ void split2(float f, unsigned short& h, unsigned short& l) {
    h = f2bf(f);
    l = f2bf(f - bf2f(h));
}

__device__ __forceinline__ void gload_lds16(const void* g, void* l) {
    __builtin_amdgcn_global_load_lds(
        (const __attribute__((address_space(1))) void*)g,
        (__attribute__((address_space(3))) void*)l,
        16, 0, 0);
}

// ---------------------------------------------------------------------------
// f32 -> bf16 elementwise convert (16B stores)
// ---------------------------------------------------------------------------
__global__ __launch_bounds__(256) void convert_bf16(
    const float* __restrict__ in, unsigned short* __restrict__ out)
{
    const int i = blockIdx.x * 256 + threadIdx.x;
    const float4 a = ((const float4*)in)[i * 2];
    const float4 b = ((const float4*)in)[i * 2 + 1];
    union { unsigned short s[8]; uint4 v; } o;
    o.s[0] = f2bf(a.x); o.s[1] = f2bf(a.y); o.s[2] = f2bf(a.z); o.s[3] = f2bf(a.w);
    o.s[4] = f2bf(b.x); o.s[5] = f2bf(b.y); o.s[6] = f2bf(b.z); o.s[7] = f2bf(b.w);
    ((uint4*)out)[i] = o.v;
}

// ---------------------------------------------------------------------------
// W [K][N] f32 -> Wt [N][K] bf16
// ---------------------------------------------------------------------------
__global__ __launch_bounds__(256) void transpose_conv(
    const float* __restrict__ W, unsigned short* __restrict__ Wt)
{
    __shared__ float tile[64][65];
    const int r0 = blockIdx.y * 64, c0 = blockIdx.x * 64;
    const int tid = threadIdx.x;
#pragma unroll
    for (int e = 0; e < 16; ++e) {
        const int idx = e * 256 + tid;
        const int r = idx >> 6, c = idx & 63;
        tile[r][c] = W[(size_t)(r0 + r) * DM + c0 + c];
    }
    __syncthreads();
#pragma unroll
    for (int e = 0; e < 16; ++e) {
        const int idx = e * 256 + tid;
        const int co = idx >> 6, ro = idx & 63;
        Wt[(size_t)(c0 + co) * DM + r0 + ro] = f2bf(tile[ro][co]);
    }
}

// ---------------------------------------------------------------------------
// bf16 MFMA GEMM (m97 structure): Y = X @ W + bias (+ optional elu+1), f32 out
// ---------------------------------------------------------------------------
__global__ __launch_bounds__(256) void gemm_mfma(
    const unsigned short* __restrict__ X,
    const unsigned short* __restrict__ Wt,
    const float* __restrict__ bias,
    float* __restrict__ Y, int act)
{
    __shared__ __align__(16) unsigned short As[128 * 32];
    __shared__ __align__(16) unsigned short Bs[128 * 32];

    const int tid = threadIdx.x;
    const int lane = tid & 63;
    const int w = tid >> 6;
    const int wr = w >> 1, wc = w & 1;
    const int fm = lane & 15;
    const int fq = lane >> 4;
    const int m0 = blockIdx.y * 128, n0 = blockIdx.x * 128;

    floatx4 acc[4][4];
#pragma unroll
    for (int i = 0; i < 4; ++i)
#pragma unroll
        for (int j = 0; j < 4; ++j) acc[i][j] = (floatx4){0.f, 0.f, 0.f, 0.f};

    const int row0 = tid >> 2;
    const int row1 = row0 + 64;
    const int slot0 = (tid & 3) ^ (row0 & 3);
    const int slot1 = (tid & 3) ^ (row1 & 3);
    const unsigned short* Xa = X + (size_t)(m0 + row0) * DM + slot0 * 8;
    const unsigned short* Xb = X + (size_t)(m0 + row1) * DM + slot1 * 8;
    const unsigned short* Wa = Wt + (size_t)(n0 + row0) * DM + slot0 * 8;
    const unsigned short* Wb = Wt + (size_t)(n0 + row1) * DM + slot1 * 8;

    const int fswz = ((fq ^ (fm & 3)) << 3);

    for (int k0 = 0; k0 < DM; k0 += 32) {
        gload_lds16(Xa + k0, As + (size_t)tid * 8);
        gload_lds16(Xb + k0, As + (size_t)(256 + tid) * 8);
        gload_lds16(Wa + k0, Bs + (size_t)tid * 8);
        gload_lds16(Wb + k0, Bs + (size_t)(256 + tid) * 8);
        __syncthreads();

        short8 af[4], bf[4];
#pragma unroll
        for (int mt = 0; mt < 4; ++mt)
            af[mt] = *(const short8*)(As + (wr * 64 + mt * 16 + fm) * 32 + fswz);
#pragma unroll
        for (int nt = 0; nt < 4; ++nt)
            bf[nt] = *(const short8*)(Bs + (wc * 64 + nt * 16 + fm) * 32 + fswz);
#pragma unroll
        for (int mt = 0; mt < 4; ++mt)
#pragma unroll
            for (int nt = 0; nt < 4; ++nt)
                acc[mt][nt] = __builtin_amdgcn_mfma_f32_16x16x32_bf16(
                    af[mt], bf[nt], acc[mt][nt], 0, 0, 0);
        __syncthreads();
    }

#pragma unroll
    for (int nt = 0; nt < 4; ++nt) {
        const int col = n0 + wc * 64 + nt * 16 + fm;
        const float bv = bias[col];
#pragma unroll
        for (int mt = 0; mt < 4; ++mt) {
            const int rbase = m0 + wr * 64 + mt * 16 + fq * 4;
#pragma unroll
            for (int r = 0; r < 4; ++r) {
                float v = acc[mt][nt][r] + bv;
                if (act) v = featf(v);
                Y[(size_t)(rbase + r) * DM + col] = v;
            }
        }
    }
}

// ===========================================================================
// chunk_state (MFMA): Mt[j][dv] = sum_t K[t][j]*V[t][dv]  (= M^T), f32 out.
// Zc[j] = sum_t K[t][j]. One block per (b,h,chunk). LDS 37 KB -> 4 blk/CU.
// ===========================================================================
__global__ __launch_bounds__(256) void chunk_state(
    const float* __restrict__ Kf, const float* __restrict__ Vf,
    float* __restrict__ Mstates, float* __restrict__ Zc)
{
    __shared__ __align__(16) char smem[37888];
    unsigned short* KTH = (unsigned short*)(smem);
    unsigned short* KTL = (unsigned short*)(smem + 9216);
    unsigned short* VTH = (unsigned short*)(smem + 18432);
    unsigned short* VTL = (unsigned short*)(smem + 27648);
    float* scratch = (float*)(smem + 36864);  // 64x4 seg totals

    const int blk = blockIdx.x;
    const int bh = blk / NC, c = blk % NC;
    const int b = bh / HH, h = bh % HH;
    const int tid = threadIdx.x;
    const int w = tid >> 6, lane = tid & 63;
    const int fm = lane & 15, fq = lane >> 4;
    const size_t gbase = ((size_t)(b * LL + c * CC)) * DM + h * HD;

    // load K,V (f32), write transposed bf16 hi/lo
    {
        const int r = tid >> 2, c0 = (tid & 3) * 16;
#pragma unroll
        for (int g = 0; g < 4; ++g) {
            const int cc0 = c0 + g * 4;
            float4 kv = *(const float4*)(Kf + gbase + (size_t)r * DM + cc0);
            float4 vv = *(const float4*)(Vf + gbase + (size_t)r * DM + cc0);
            float ka[4] = {kv.x, kv.y, kv.z, kv.w};
            float va[4] = {vv.x, vv.y, vv.z, vv.w};
#pragma unroll
            for (int e = 0; e < 4; ++e) {
                unsigned short hh, ll;
                split2(ka[e], hh, ll);
                KTH[(cc0 + e) * PS + r] = hh; KTL[(cc0 + e) * PS + r] = ll;
                split2(va[e], hh, ll);
                VTH[(cc0 + e) * PS + r] = hh; VTL[(cc0 + e) * PS + r] = ll;
            }
        }
    }
    // Zc partials: thread (s=tid>>6, j=tid&63) sums 16 rows of its column (L2-warm)
    {
        const int s = tid >> 6, j = tid & 63;
        float z = 0.f;
#pragma unroll
        for (int t = 0; t < 16; ++t)
            z += Kf[gbase + (size_t)(s * 16 + t) * DM + j];
        scratch[s * 64 + j] = z;
    }
    __syncthreads();

    if (tid < 64) {
        Zc[(size_t)blk * 64 + tid] = scratch[tid] + scratch[64 + tid] +
                                     scratch[128 + tid] + scratch[192 + tid];
    }

    // MFMA: C[j][dv] = sum_t KT[j][t] * VT[dv][t]; wave strip j in [16w,16w+16)
    floatx4 acc[4];
#pragma unroll
    for (int nt = 0; nt < 4; ++nt) acc[nt] = (floatx4){0.f, 0.f, 0.f, 0.f};
    short8 aH[2], aL[2];
#pragma unroll
    for (int ks = 0; ks < 2; ++ks) {
        aH[ks] = *(const short8*)(KTH + (16 * w + fm) * PS + ks * 32 + fq * 8);
        aL[ks] = *(const short8*)(KTL + (16 * w + fm) * PS + ks * 32 + fq * 8);
    }
#pragma unroll
    for (int nt = 0; nt < 4; ++nt) {
#pragma unroll
        for (int ks = 0; ks < 2; ++ks) {
            short8 bH = *(const short8*)(VTH + (nt * 16 + fm) * PS + ks * 32 + fq * 8);
            short8 bL = *(const short8*)(VTL + (nt * 16 + fm) * PS + ks * 32 + fq * 8);
            acc[nt] = __builtin_amdgcn_mfma_f32_16x16x32_bf16(aH[ks], bH, acc[nt], 0, 0, 0);
            acc[nt] = __builtin_amdgcn_mfma_f32_16x16x32_bf16(aH[ks], bL, acc[nt], 0, 0, 0);
            acc[nt] = __builtin_amdgcn_mfma_f32_16x16x32_bf16(aL[ks], bH, acc[nt], 0, 0, 0);
        }
    }
    // epilogue: C layout col=fm(+16nt)=dv, row=fq*4+r(+16w)=j
    float* Mout = Mstates + (size_t)blk * 4096;
#pragma unroll
    for (int nt = 0; nt < 4; ++nt) {
        const int dv = nt * 16 + fm;
#pragma unroll
        for (int r = 0; r < 4; ++r) {
            const int j = 16 * w + fq * 4 + r;
            Mout[j * 64 + dv] = acc[nt][r];
        }
    }
}

// ---------------------------------------------------------------------------
// exclusive prefix over chunks (elementwise on Mt layout) + Z prefix
// ---------------------------------------------------------------------------
__global__ __launch_bounds__(256) void prefix_state(
    float* __restrict__ Mstates, float* __restrict__ Zc)
{
    const int bh = blockIdx.x >> 4;
    const int slice = blockIdx.x & 15;
    const int off = slice * 256 + threadIdx.x;
    float run = 0.f;
    float* base = Mstates + (size_t)bh * NC * 4096 + off;
    for (int c = 0; c < NC; ++c) {
        const float v = base[(size_t)c * 4096];
        base[(size_t)c * 4096] = run;
        run += v;
    }
    if (slice == 0 && threadIdx.x < 64) {
        float z = 0.f;
        float* zb = Zc + (size_t)bh * NC * 64 + threadIdx.x;
        for (int c = 0; c < NC; ++c) {
            const float v = zb[c * 64];
            zb[c * 64] = z;
            z += v;
        }
    }
}

// ===========================================================================
// chunk_attn (MFMA, hi/lo split):
//  stage1: A = Q @ V^T (tril-masked)            [24 MFMA/wave]
//  stage2: num = [Q|A] @ rows([Mt|KT])          [48 MFMA/wave]
//  out[i][j] = num / (q_ij * Z_ij + eps) -> bf16
// LDS 72 KB -> 2 blk/CU. One block per (b,h,chunk).
// ===========================================================================
__global__ __launch_bounds__(256) void chunk_attn(
    const float* __restrict__ Qf, const float* __restrict__ Kf,
    const float* __restrict__ Vf, const float* __restrict__ Mprev,
    const float* __restrict__ Zprev, unsigned short* __restrict__ Outb)
{
    __shared__ __align__(16) char smem[73728];
    unsigned short* QH  = (unsigned short*)(smem);            // rows [i][dv]
    unsigned short* QL  = (unsigned short*)(smem + 9216);
    unsigned short* VH  = (unsigned short*)(smem + 18432);    // rows [t][dv]; later Mt rows [j][dv]
    unsigned short* VL  = (unsigned short*)(smem + 27648);
    unsigned short* KTH = (unsigned short*)(smem + 36864);    // rows [j][t]
    unsigned short* KTL = (unsigned short*)(smem + 46080);
    unsigned short* AH  = (unsigned short*)(smem + 55296);    // rows [i][t]
    unsigned short* AL  = (unsigned short*)(smem + 64512);
    float* Zf      = (float*)(smem + 36864);                  // 64x64 f32, over KT (late)
    float* scratch = (float*)(smem + 55296);                  // 4x64 seg totals, over A (early)

    const int blk = blockIdx.x;
    const int bh = blk / NC, c = blk % NC;
    const int b = bh / HH, h = bh % HH;
    const int tid = threadIdx.x;
    const int w = tid >> 6, lane = tid & 63;
    const int fm = lane & 15, fq = lane >> 4;
    const size_t gbase = ((size_t)(b * LL + c * CC)) * DM + h * HD;

    const int lr = tid >> 2, lc0 = (tid & 3) * 16;  // load mapping

    // ---- phase 0: load Q,K,V; write QH/QL, VH/VL (rows), KTH/KTL (transposed)
    float4 mpre[4];  // prefetch Mt f32 (written to LDS after barrier2)
    {
        const float* Mp = Mprev + (size_t)blk * 4096;
#pragma unroll
        for (int g = 0; g < 4; ++g)
            mpre[g] = *(const float4*)(Mp + lr * 64 + lc0 + g * 4);
    }
#pragma unroll
    for (int g = 0; g < 4; ++g) {
        const int cc0 = lc0 + g * 4;
        float4 qv = *(const float4*)(Qf + gbase + (size_t)lr * DM + cc0);
        float4 vv = *(const float4*)(Vf + gbase + (size_t)lr * DM + cc0);
        float4 kv = *(const float4*)(Kf + gbase + (size_t)lr * DM + cc0);
        float qa[4] = {qv.x, qv.y, qv.z, qv.w};
        float va[4] = {vv.x, vv.y, vv.z, vv.w};
        float ka[4] = {kv.x, kv.y, kv.z, kv.w};
        union { unsigned short s[4]; uint2 v; } qh, ql, vh, vl;
#pragma unroll
        for (int e = 0; e < 4; ++e) {
            split2(qa[e], qh.s[e], ql.s[e]);
            split2(va[e], vh.s[e], vl.s[e]);
            unsigned short hh, ll;
            split2(ka[e], hh, ll);
            KTH[(cc0 + e) * PS + lr] = hh;
            KTL[(cc0 + e) * PS + lr] = ll;
        }
        *(uint2*)(QH + lr * PS + cc0) = qh.v;
        *(uint2*)(QL + lr * PS + cc0) = ql.v;
        *(uint2*)(VH + lr * PS + cc0) = vh.v;
        *(uint2*)(VL + lr * PS + cc0) = vl.v;
    }
    // Z partials: thread (s,j): inclusive cumsum of its 16 rows (column j)
    const int zs = tid >> 6, zj = tid & 63;
    float zpart[16];
    {
        float run = 0.f;
#pragma unroll
        for (int t = 0; t < 16; ++t) {
            run += Kf[gbase + (size_t)(zs * 16 + t) * DM + zj];
            zpart[t] = run;
        }
        scratch[zs * 64 + zj] = run;
    }
    const float zp = Zprev[(size_t)blk * 64 + zj];
    __syncthreads();  // barrier 1

    // finalize absolute Z into registers
    {
        float off = zp;
        for (int ss = 0; ss < 4; ++ss)
            if (ss < zs) off += scratch[ss * 64 + zj];
#pragma unroll
        for (int t = 0; t < 16; ++t) zpart[t] += off;
    }

    // ---- stage 1: A = Q @ V^T (3-term split)
    floatx4 acc1[4];
#pragma unroll
    for (int nt = 0; nt < 4; ++nt) acc1[nt] = (floatx4){0.f, 0.f, 0.f, 0.f};
    {
        short8 aH[2], aL[2];
#pragma unroll
        for (int ks = 0; ks < 2; ++ks) {
            aH[ks] = *(const short8*)(QH + (16 * w + fm) * PS + ks * 32 + fq * 8);
            aL[ks] = *(const short8*)(QL + (16 * w + fm) * PS + ks * 32 + fq * 8);
        }
#pragma unroll
        for (int nt = 0; nt < 4; ++nt) {
#pragma unroll
            for (int ks = 0; ks < 2; ++ks) {
                short8 bH = *(const short8*)(VH + (nt * 16 + fm) * PS + ks * 32 + fq * 8);
                short8 bL = *(const short8*)(VL + (nt * 16 + fm) * PS + ks * 32 + fq * 8);
                acc1[nt] = __builtin_amdgcn_mfma_f32_16x16x32_bf16(aH[ks], bH, acc1[nt], 0, 0, 0);
                acc1[nt] = __builtin_amdgcn_mfma_f32_16x16x32_bf16(aH[ks], bL, acc1[nt], 0, 0, 0);
                acc1[nt] = __builtin_amdgcn_mfma_f32_16x16x32_bf16(aL[ks], bH, acc1[nt], 0, 0, 0);
            }
        }
    }
    __syncthreads();  // barrier 2 (scratch reads + V reads done)

    // write tril(A) hi/lo; write Mt hi/lo over V region
#pragma unroll
    for (int nt = 0; nt < 4; ++nt) {
        const int t = nt * 16 + fm;
#pragma unroll
        for (int r = 0; r < 4; ++r) {
            const int i = 16 * w + fq * 4 + r;
            const float v = (t <= i) ? acc1[nt][r] : 0.f;
            unsigned short hh, ll;
            split2(v, hh, ll);
            AH[i * PS + t] = hh;
            AL[i * PS + t] = ll;
        }
    }
#pragma unroll
    for (int g = 0; g < 4; ++g) {
        const int cc0 = lc0 + g * 4;
        float ma[4] = {mpre[g].x, mpre[g].y, mpre[g].z, mpre[g].w};
        union { unsigned short s[4]; uint2 v; } mh, ml;
#pragma unroll
        for (int e = 0; e < 4; ++e) split2(ma[e], mh.s[e], ml.s[e]);
        *(uint2*)(VH + lr * PS + cc0) = mh.v;  // MtH rows [j][dv]
        *(uint2*)(VL + lr * PS + cc0) = ml.v;
    }
    __syncthreads();  // barrier 3

    // ---- stage 2: num = [Q|A](i,k) . rows([Mt|KT])(j,k), K=128
    floatx4 acc2[4];
#pragma unroll
    for (int nt = 0; nt < 4; ++nt) acc2[nt] = (floatx4){0.f, 0.f, 0.f, 0.f};
    {
        short8 aH[4], aL[4];
#pragma unroll
        for (int ks = 0; ks < 2; ++ks) {
            aH[ks] = *(const short8*)(QH + (16 * w + fm) * PS + ks * 32 + fq * 8);
            aL[ks] = *(const short8*)(QL + (16 * w + fm) * PS + ks * 32 + fq * 8);
            aH[2 + ks] = *(const short8*)(AH + (16 * w + fm) * PS + ks * 32 + fq * 8);
            aL[2 + ks] = *(const short8*)(AL + (16 * w + fm) * PS + ks * 32 + fq * 8);
        }
#pragma unroll
        for (int nt = 0; nt < 4; ++nt) {
            const int rb = (nt * 16 + fm) * PS + fq * 8;
#pragma unroll
            for (int ks = 0; ks < 4; ++ks) {
                const unsigned short* BH = (ks < 2) ? VH : KTH;
                const unsigned short* BL = (ks < 2) ? VL : KTL;
                const int ko = (ks & 1) * 32;
                short8 bH = *(const short8*)(BH + rb + ko);
                short8 bL = *(const short8*)(BL + rb + ko);
                acc2[nt] = __builtin_amdgcn_mfma_f32_16x16x32_bf16(aH[ks], bH, acc2[nt], 0, 0, 0);
                acc2[nt] = __builtin_amdgcn_mfma_f32_16x16x32_bf16(aH[ks], bL, acc2[nt], 0, 0, 0);
                acc2[nt] = __builtin_amdgcn_mfma_f32_16x16x32_bf16(aL[ks], bH, acc2[nt], 0, 0, 0);
            }
        }
    }
    __syncthreads();  // barrier 4 (KT/Mt reads done)

    // write absolute Z over KT region
#pragma unroll
    for (int t = 0; t < 16; ++t)
        Zf[(zs * 16 + t) * 64 + zj] = zpart[t];
    __syncthreads();  // barrier 5

    // epilogue: divide and store bf16
#pragma unroll
    for (int nt = 0; nt < 4; ++nt) {
        const int j = nt * 16 + fm;
#pragma unroll
        for (int r = 0; r < 4; ++r) {
            const int i = 16 * w + fq * 4 + r;
            const float q = bf2f(QH[i * PS + j]) + bf2f(QL[i * PS + j]);
            const float z = Zf[i * 64 + j];
            const float denom = fmaf(q, z, EPSC);
            Outb[gbase + (size_t)i * DM + j] = f2bf(acc2[nt][r] / denom);
        }
    }
}

// ---------------------------------------------------------------------------
// Launch
// ---------------------------------------------------------------------------
extern "C" void kernel_launch(void* const* d_in, const int* in_sizes, int n_in,
                              void* d_out, int out_size, void* d_ws, size_t ws_size,
                              hipStream_t stream)
{
    (void)in_sizes; (void)n_in; (void)out_size; (void)ws_size;

    const float* queries = (const float*)d_in[0];
    const float* keys    = (const float*)d_in[1];
    const float* values  = (const float*)d_in[2];
    const float* Wq = (const float*)d_in[3];
    const float* bq = (const float*)d_in[4];
    const float* Wk = (const float*)d_in[5];
    const float* bk = (const float*)d_in[6];
    const float* Wv = (const float*)d_in[7];
    const float* bv = (const float*)d_in[8];
    const float* Wo = (const float*)d_in[9];
    const float* bo = (const float*)d_in[10];

    char* ws = (char*)d_ws;
    const size_t MB = 1u << 20;
    unsigned short* qb  = (unsigned short*)(ws);             // 16 MB
    unsigned short* kb  = (unsigned short*)(ws + 16 * MB);   // 16 MB
    unsigned short* vb  = (unsigned short*)(ws + 32 * MB);   // 16 MB
    unsigned short* Wqt = (unsigned short*)(ws + 48 * MB);
    unsigned short* Wkt = (unsigned short*)(ws + 50 * MB);
    unsigned short* Wvt = (unsigned short*)(ws + 52 * MB);
    unsigned short* Wot = (unsigned short*)(ws + 54 * MB);
    float* Qf = (float*)(ws + 56 * MB);                      // 32 MB
    float* Kf = (float*)(ws + 88 * MB);                      // 32 MB
    float* Vf = (float*)(ws + 120 * MB);                     // 32 MB
    float* Zc = (float*)(ws + 152 * MB);                     // 0.5 MB
    unsigned short* attnb = (unsigned short*)(ws);           // reuse qb
    float* Mst = (float*)(ws + 16 * MB);                     // reuse kb+vb (32 MB)

    const dim3 gblk(256);
    const int NCONV = (BB * LL * DM) / (8 * 256);
    const dim3 gT(16, 16);
    const dim3 gG(DM / 128, (BB * LL) / 128);

    convert_bf16<<<dim3(NCONV), gblk, 0, stream>>>(queries, qb);
    convert_bf16<<<dim3(NCONV), gblk, 0, stream>>>(keys, kb);
    convert_bf16<<<dim3(NCONV), gblk, 0, stream>>>(values, vb);
    transpose_conv<<<gT, gblk, 0, stream>>>(Wq, Wqt);
    transpose_conv<<<gT, gblk, 0, stream>>>(Wk, Wkt);
    transpose_conv<<<gT, gblk, 0, stream>>>(Wv, Wvt);
    transpose_conv<<<gT, gblk, 0, stream>>>(Wo, Wot);

    gemm_mfma<<<gG, gblk, 0, stream>>>(qb, Wqt, bq, Qf, 1);
    gemm_mfma<<<gG, gblk, 0, stream>>>(kb, Wkt, bk, Kf, 1);
    gemm_mfma<<<gG, gblk, 0, stream>>>(vb, Wvt, bv, Vf, 0);

    chunk_state<<<dim3(BB * HH * NC), gblk, 0, stream>>>(Kf, Vf, Mst, Zc);
    prefix_state<<<dim3(BB * HH * 16), gblk, 0, stream>>>(Mst, Zc);
    chunk_attn<<<dim3(BB * HH * NC), gblk, 0, stream>>>(Qf, Kf, Vf, Mst, Zc, attnb);

    gemm_mfma<<<gG, gblk, 0, stream>>>(attnb, Wot, bo, (float*)d_out, 0);
}

// Round 4
// 369.303 us; speedup vs baseline: 3.0773x; 1.0007x over previous
//
#include <hip/hip_runtime.h>
#include <math.h>

// Problem constants
#define DM 1024      // d_model
#define LL 2048      // sequence length
#define BB 4         // batch
#define HH 16        // heads
#define HD 64        // head dim
#define CC 64        // chunk size
#define NC (LL / CC) // 32 chunks
#define EPSC 1e-6f
#define PS 72        // padded LDS stride (shorts) for 64-wide bf16 tiles

typedef __attribute__((ext_vector_type(8))) short short8;   // 8 bf16 (4 VGPRs)
typedef __attribute__((ext_vector_type(4))) float floatx4;  // MFMA accumulator

__device__ __forceinline__ float featf(float x) { return x > 0.f ? x + 1.f : __expf(x); }

// round-to-nearest-even f32 -> bf16 bits
__device__ __forceinline__ unsigned short f2bf(float f) {
    unsigned int u = __builtin_bit_cast(unsigned int, f);
    u = (u + 0x7FFFu + ((u >> 16) & 1u)) >> 16;
    return (unsigned short)u;
}
__device__ __forceinline__ float bf2f(unsigned short h) {
    return __builtin_bit_cast(float, (unsigned int)h << 16);
}
// split f32 into bf16 hi + bf16 lo (f ~= hi + lo)
__device__ __forceinline__ void split2(float f, unsigned short& h, unsigned short& l) {
    h = f2bf(f);
    l = f2bf(f - bf2f(h));
}

__device__ __forceinline__ void gload_lds16(const void* g, void* l) {
    __builtin_amdgcn_global_load_lds(
        (const __attribute__((address_space(1))) void*)g,
        (__attribute__((address_space(3))) void*)l,
        16, 0, 0);
}

// ---------------------------------------------------------------------------
// fused f32 -> bf16 convert for q,k,v (blockIdx.x>>12 selects tensor)
// ---------------------------------------------------------------------------
__global__ __launch_bounds__(256) void convert3(
    const float* __restrict__ a, const float* __restrict__ b,
    const float* __restrict__ c, unsigned short* __restrict__ oa,
    unsigned short* __restrict__ ob, unsigned short* __restrict__ oc)
{
    const int blk = blockIdx.x;
    const int sel = blk >> 12;
    const float* src = (sel == 0) ? a : (sel == 1) ? b : c;
    unsigned short* dst = (sel == 0) ? oa : (sel == 1) ? ob : oc;
    const int i = (blk & 4095) * 256 + threadIdx.x;
    const float4 x = ((const float4*)src)[i * 2];
    const float4 y = ((const float4*)src)[i * 2 + 1];
    union { unsigned short s[8]; uint4 v; } o;
    o.s[0] = f2bf(x.x); o.s[1] = f2bf(x.y); o.s[2] = f2bf(x.z); o.s[3] = f2bf(x.w);
    o.s[4] = f2bf(y.x); o.s[5] = f2bf(y.y); o.s[6] = f2bf(y.z); o.s[7] = f2bf(y.w);
    ((uint4*)dst)[i] = o.v;
}

// ---------------------------------------------------------------------------
// fused weight transpose+convert: W [K][N] f32 -> Wt [N][K] bf16, 4 weights
// ---------------------------------------------------------------------------
__global__ __launch_bounds__(256) void transpose4(
    const float* __restrict__ W0, const float* __restrict__ W1,
    const float* __restrict__ W2, const float* __restrict__ W3,
    unsigned short* __restrict__ T0, unsigned short* __restrict__ T1,
    unsigned short* __restrict__ T2, unsigned short* __restrict__ T3)
{
    __shared__ float tile[64][65];
    const int sel = blockIdx.z;
    const float* W = (sel == 0) ? W0 : (sel == 1) ? W1 : (sel == 2) ? W2 : W3;
    unsigned short* Wt = (sel == 0) ? T0 : (sel == 1) ? T1 : (sel == 2) ? T2 : T3;
    const int r0 = blockIdx.y * 64, c0 = blockIdx.x * 64;
    const int tid = threadIdx.x;
#pragma unroll
    for (int e = 0; e < 16; ++e) {
        const int idx = e * 256 + tid;
        const int r = idx >> 6, c = idx & 63;
        tile[r][c] = W[(size_t)(r0 + r) * DM + c0 + c];
    }
    __syncthreads();
#pragma unroll
    for (int e = 0; e < 16; ++e) {
        const int idx = e * 256 + tid;
        const int co = idx >> 6, ro = idx & 63;
        Wt[(size_t)(c0 + co) * DM + r0 + ro] = f2bf(tile[ro][co]);
    }
}

// ---------------------------------------------------------------------------
// bf16 MFMA GEMM: Y = X @ W + bias (+ optional elu+1), f32 out.
// layout=0: row-major Y[M][1024].
// layout=1: per-chunk transposed KT layout Y[(b*16+h)*32+c][j][t] (float4).
// ---------------------------------------------------------------------------
__global__ __launch_bounds__(256) void gemm_mfma(
    const unsigned short* __restrict__ X,
    const unsigned short* __restrict__ Wt,
    const float* __restrict__ bias,
    float* __restrict__ Y, int act, int layout)
{
    __shared__ __align__(16) unsigned short As[128 * 32];
    __shared__ __align__(16) unsigned short Bs[128 * 32];

    const int tid = threadIdx.x;
    const int lane = tid & 63;
    const int w = tid >> 6;
    const int wr = w >> 1, wc = w & 1;
    const int fm = lane & 15;
    const int fq = lane >> 4;
    const int m0 = blockIdx.y * 128, n0 = blockIdx.x * 128;

    floatx4 acc[4][4];
#pragma unroll
    for (int i = 0; i < 4; ++i)
#pragma unroll
        for (int j = 0; j < 4; ++j) acc[i][j] = (floatx4){0.f, 0.f, 0.f, 0.f};

    const int row0 = tid >> 2;
    const int row1 = row0 + 64;
    const int slot0 = (tid & 3) ^ (row0 & 3);
    const int slot1 = (tid & 3) ^ (row1 & 3);
    const unsigned short* Xa = X + (size_t)(m0 + row0) * DM + slot0 * 8;
    const unsigned short* Xb = X + (size_t)(m0 + row1) * DM + slot1 * 8;
    const unsigned short* Wa = Wt + (size_t)(n0 + row0) * DM + slot0 * 8;
    const unsigned short* Wb = Wt + (size_t)(n0 + row1) * DM + slot1 * 8;

    const int fswz = ((fq ^ (fm & 3)) << 3);

    for (int k0 = 0; k0 < DM; k0 += 32) {
        gload_lds16(Xa + k0, As + (size_t)tid * 8);
        gload_lds16(Xb + k0, As + (size_t)(256 + tid) * 8);
        gload_lds16(Wa + k0, Bs + (size_t)tid * 8);
        gload_lds16(Wb + k0, Bs + (size_t)(256 + tid) * 8);
        __syncthreads();

        short8 af[4], bf[4];
#pragma unroll
        for (int mt = 0; mt < 4; ++mt)
            af[mt] = *(const short8*)(As + (wr * 64 + mt * 16 + fm) * 32 + fswz);
#pragma unroll
        for (int nt = 0; nt < 4; ++nt)
            bf[nt] = *(const short8*)(Bs + (wc * 64 + nt * 16 + fm) * 32 + fswz);
#pragma unroll
        for (int mt = 0; mt < 4; ++mt)
#pragma unroll
            for (int nt = 0; nt < 4; ++nt)
                acc[mt][nt] = __builtin_amdgcn_mfma_f32_16x16x32_bf16(
                    af[mt], bf[nt], acc[mt][nt], 0, 0, 0);
        __syncthreads();
    }

    if (layout == 0) {
#pragma unroll
        for (int nt = 0; nt < 4; ++nt) {
            const int col = n0 + wc * 64 + nt * 16 + fm;
            const float bv = bias[col];
#pragma unroll
            for (int mt = 0; mt < 4; ++mt) {
                const int rbase = m0 + wr * 64 + mt * 16 + fq * 4;
#pragma unroll
                for (int r = 0; r < 4; ++r) {
                    float v = acc[mt][nt][r] + bv;
                    if (act) v = featf(v);
                    Y[(size_t)(rbase + r) * DM + col] = v;
                }
            }
        }
    } else {
        // KT-chunk layout: rows of tile = seq positions; 4 consecutive rows
        // per reg group = contiguous t -> float4 stores.
        const int b = m0 >> 11;                       // batch
        const int cch = ((m0 & 2047) >> 6) + wr;      // chunk
        const int h = (n0 >> 6) + wc;                 // head
        float* base = Y + ((size_t)((b * 16 + h) * 32 + cch)) * 4096;
#pragma unroll
        for (int nt = 0; nt < 4; ++nt) {
            const int j = nt * 16 + fm;
            const float bv = bias[n0 + wc * 64 + nt * 16 + fm];
#pragma unroll
            for (int mt = 0; mt < 4; ++mt) {
                float4 o;
                o.x = acc[mt][nt][0] + bv; o.y = acc[mt][nt][1] + bv;
                o.z = acc[mt][nt][2] + bv; o.w = acc[mt][nt][3] + bv;
                if (act) { o.x = featf(o.x); o.y = featf(o.y);
                           o.z = featf(o.z); o.w = featf(o.w); }
                *(float4*)(base + j * 64 + mt * 16 + fq * 4) = o;
            }
        }
    }
}

// ===========================================================================
// chunk_state: Mt[j][dv] = sum_t K[t][j]*V[t][dv], Zc[j] = sum_t K[t][j].
// Kc input is pre-transposed KT-chunk layout [blk][j][t]. V transposed in LDS
// with e-rotation (2-way banks). LDS 37.9 KB -> 4 blk/CU.
// ===========================================================================
__global__ __launch_bounds__(256) void chunk_state(
    const float* __restrict__ Kc, const float* __restrict__ Vf,
    float* __restrict__ Mstates, float* __restrict__ Zc)
{
    __shared__ __align__(16) char smem[37888];
    unsigned short* KTH = (unsigned short*)(smem);
    unsigned short* KTL = (unsigned short*)(smem + 9216);
    unsigned short* VTH = (unsigned short*)(smem + 18432);
    unsigned short* VTL = (unsigned short*)(smem + 27648);
    float* scratch = (float*)(smem + 36864);

    const int blk = blockIdx.x;
    const int bh = blk / NC, c = blk % NC;
    const int b = bh / HH, h = bh % HH;
    const int tid = threadIdx.x;
    const int w = tid >> 6;
    const int lane = tid & 63;
    const int fm = lane & 15, fq = lane >> 4;
    const size_t gbase = ((size_t)(b * LL + c * CC)) * DM + h * HD;
    const float* Kblk = Kc + (size_t)blk * 4096;

    const int lr = tid >> 2, lc0 = (tid & 3) * 16;

    // KT rows direct (vectorized): row j=lr, t in [lc0, lc0+16)
    {
        float ka[16];
#pragma unroll
        for (int g = 0; g < 4; ++g)
            *(float4*)(ka + g * 4) = *(const float4*)(Kblk + lr * 64 + lc0 + g * 4);
        union { unsigned short s[16]; uint4 v[2]; } hh, ll;
#pragma unroll
        for (int e = 0; e < 16; ++e) split2(ka[e], hh.s[e], ll.s[e]);
        *(uint4*)(KTH + lr * PS + lc0) = hh.v[0];
        *(uint4*)(KTH + lr * PS + lc0 + 8) = hh.v[1];
        *(uint4*)(KTL + lr * PS + lc0) = ll.v[0];
        *(uint4*)(KTL + lr * PS + lc0 + 8) = ll.v[1];
    }
    // V rows -> transposed VT with e-rotation
    {
        float va[16];
#pragma unroll
        for (int g = 0; g < 4; ++g)
            *(float4*)(va + g * 4) = *(const float4*)(Vf + gbase + (size_t)lr * DM + lc0 + g * 4);
#pragma unroll
        for (int g = 0; g < 4; ++g)
#pragma unroll
            for (int e0 = 0; e0 < 4; ++e0) {
                const int e = g * 4 + ((e0 + tid) & 3);
                unsigned short hh, ll;
                split2(va[e], hh, ll);
                VTH[(lc0 + e) * PS + lr] = hh;
                VTL[(lc0 + e) * PS + lr] = ll;
            }
    }
    // Z partials from contiguous KT rows
    {
        const int zj = tid & 63, zs = tid >> 6;
        float z = 0.f;
#pragma unroll
        for (int g = 0; g < 4; ++g) {
            float4 kv = *(const float4*)(Kblk + zj * 64 + zs * 16 + g * 4);
            z += kv.x + kv.y + kv.z + kv.w;
        }
        scratch[zs * 64 + zj] = z;
    }
    __syncthreads();

    if (tid < 64) {
        Zc[(size_t)blk * 64 + tid] = scratch[tid] + scratch[64 + tid] +
                                     scratch[128 + tid] + scratch[192 + tid];
    }

    // MFMA: C[j][dv], A = KT rows, B = VT rows
    floatx4 acc[4];
#pragma unroll
    for (int nt = 0; nt < 4; ++nt) acc[nt] = (floatx4){0.f, 0.f, 0.f, 0.f};
    short8 aH[2], aL[2];
#pragma unroll
    for (int ks = 0; ks < 2; ++ks) {
        aH[ks] = *(const short8*)(KTH + (16 * w + fm) * PS + ks * 32 + fq * 8);
        aL[ks] = *(const short8*)(KTL + (16 * w + fm) * PS + ks * 32 + fq * 8);
    }
#pragma unroll
    for (int nt = 0; nt < 4; ++nt) {
#pragma unroll
        for (int ks = 0; ks < 2; ++ks) {
            short8 bH = *(const short8*)(VTH + (nt * 16 + fm) * PS + ks * 32 + fq * 8);
            short8 bL = *(const short8*)(VTL + (nt * 16 + fm) * PS + ks * 32 + fq * 8);
            acc[nt] = __builtin_amdgcn_mfma_f32_16x16x32_bf16(aH[ks], bH, acc[nt], 0, 0, 0);
            acc[nt] = __builtin_amdgcn_mfma_f32_16x16x32_bf16(aH[ks], bL, acc[nt], 0, 0, 0);
            acc[nt] = __builtin_amdgcn_mfma_f32_16x16x32_bf16(aL[ks], bH, acc[nt], 0, 0, 0);
        }
    }
    float* Mout = Mstates + (size_t)blk * 4096;
#pragma unroll
    for (int nt = 0; nt < 4; ++nt) {
        const int dv = nt * 16 + fm;
#pragma unroll
        for (int r = 0; r < 4; ++r) {
            const int j = 16 * w + fq * 4 + r;
            Mout[j * 64 + dv] = acc[nt][r];
        }
    }
}

// ---------------------------------------------------------------------------
// exclusive prefix over chunks + Z prefix
// ---------------------------------------------------------------------------
__global__ __launch_bounds__(256) void prefix_state(
    float* __restrict__ Mstates, float* __restrict__ Zc)
{
    const int bh = blockIdx.x >> 4;
    const int slice = blockIdx.x & 15;
    const int off = slice * 256 + threadIdx.x;
    float run = 0.f;
    float* base = Mstates + (size_t)bh * NC * 4096 + off;
    for (int c = 0; c < NC; ++c) {
        const float v = base[(size_t)c * 4096];
        base[(size_t)c * 4096] = run;
        run += v;
    }
    if (slice == 0 && threadIdx.x < 64) {
        float z = 0.f;
        float* zb = Zc + (size_t)bh * NC * 64 + threadIdx.x;
        for (int c = 0; c < NC; ++c) {
            const float v = zb[c * 64];
            zb[c * 64] = z;
            z += v;
        }
    }
}

// ===========================================================================
// chunk_attn v2: Q frags from global regs (reused stage1+2), KT pre-transposed,
// f32 Q tile for epilogue, Zf over dead KT region. LDS 72.7 KB.
// ===========================================================================
__global__ __launch_bounds__(256) void chunk_attn(
    const float* __restrict__ Qf, const float* __restrict__ Kc,
    const float* __restrict__ Vf, const float* __restrict__ Mprev,
    const float* __restrict__ Zprev, unsigned short* __restrict__ Outb)
{
    __shared__ __align__(16) char smem[72704];
    unsigned short* VH  = (unsigned short*)(smem);            // V rows; later Mt rows
    unsigned short* VL  = (unsigned short*)(smem + 9216);
    unsigned short* KTH = (unsigned short*)(smem + 18432);    // KT rows [j][t]
    unsigned short* KTL = (unsigned short*)(smem + 27648);
    unsigned short* AH  = (unsigned short*)(smem + 36864);    // A rows [i][t]
    unsigned short* AL  = (unsigned short*)(smem + 46080);
    float* Qs = (float*)(smem + 55296);                       // 64 x 68 f32
    float* Zf = (float*)(smem + 18432);                       // 64 x 67 f32, over KT (late)
    float* scratch = (float*)(smem + 36864);                  // 4x64, over A (early)

    const int blk = blockIdx.x;
    const int bh = blk / NC, c = blk % NC;
    const int b = bh / HH, h = bh % HH;
    const int tid = threadIdx.x;
    const int w = tid >> 6, lane = tid & 63;
    const int fm = lane & 15, fq = lane >> 4;
    const size_t gbase = ((size_t)(b * LL + c * CC)) * DM + h * HD;
    const float* Kblk = Kc + (size_t)blk * 4096;

    const int lr = tid >> 2, lc0 = (tid & 3) * 16;

    // ---- phase 0
    float4 mpre[4];
    {
        const float* Mp = Mprev + (size_t)blk * 4096;
#pragma unroll
        for (int g = 0; g < 4; ++g)
            mpre[g] = *(const float4*)(Mp + lr * 64 + lc0 + g * 4);
    }
    // V rows -> VH/VL (vector)
    {
        float va[16];
#pragma unroll
        for (int g = 0; g < 4; ++g)
            *(float4*)(va + g * 4) = *(const float4*)(Vf + gbase + (size_t)lr * DM + lc0 + g * 4);
        union { unsigned short s[16]; uint4 v[2]; } hh, ll;
#pragma unroll
        for (int e = 0; e < 16; ++e) split2(va[e], hh.s[e], ll.s[e]);
        *(uint4*)(VH + lr * PS + lc0) = hh.v[0];
        *(uint4*)(VH + lr * PS + lc0 + 8) = hh.v[1];
        *(uint4*)(VL + lr * PS + lc0) = ll.v[0];
        *(uint4*)(VL + lr * PS + lc0 + 8) = ll.v[1];
    }
    // KT rows -> KTH/KTL (vector)
    {
        float ka[16];
#pragma unroll
        for (int g = 0; g < 4; ++g)
            *(float4*)(ka + g * 4) = *(const float4*)(Kblk + lr * 64 + lc0 + g * 4);
        union { unsigned short s[16]; uint4 v[2]; } hh, ll;
#pragma unroll
        for (int e = 0; e < 16; ++e) split2(ka[e], hh.s[e], ll.s[e]);
        *(uint4*)(KTH + lr * PS + lc0) = hh.v[0];
        *(uint4*)(KTH + lr * PS + lc0 + 8) = hh.v[1];
        *(uint4*)(KTL + lr * PS + lc0) = ll.v[0];
        *(uint4*)(KTL + lr * PS + lc0 + 8) = ll.v[1];
    }
    // Q rows -> f32 tile (for epilogue)
    {
#pragma unroll
        for (int g = 0; g < 4; ++g) {
            float4 qv = *(const float4*)(Qf + gbase + (size_t)lr * DM + lc0 + g * 4);
            *(float4*)(Qs + lr * 68 + lc0 + g * 4) = qv;
        }
    }
    // Q fragments from global into regs (row 16w+fm)
    short8 qH[2], qL[2];
    {
        const float* qrow = Qf + gbase + (size_t)(16 * w + fm) * DM;
#pragma unroll
        for (int ks = 0; ks < 2; ++ks) {
            float qa[8];
            *(float4*)(qa)     = *(const float4*)(qrow + ks * 32 + fq * 8);
            *(float4*)(qa + 4) = *(const float4*)(qrow + ks * 32 + fq * 8 + 4);
            union { unsigned short s[8]; short8 v; } hh, ll;
#pragma unroll
            for (int e = 0; e < 8; ++e) split2(qa[e], hh.s[e], ll.s[e]);
            qH[ks] = hh.v; qL[ks] = ll.v;
        }
    }
    // Z partials: contiguous KT reads, inclusive cumsum over 16 t's
    const int zj = tid & 63, zs = tid >> 6;
    float zpart[16];
    {
        float ka[16];
#pragma unroll
        for (int g = 0; g < 4; ++g)
            *(float4*)(ka + g * 4) = *(const float4*)(Kblk + zj * 64 + zs * 16 + g * 4);
        float run = 0.f;
#pragma unroll
        for (int t = 0; t < 16; ++t) { run += ka[t]; zpart[t] = run; }
        scratch[zs * 64 + zj] = run;
    }
    const float zp = Zprev[(size_t)blk * 64 + zj];
    __syncthreads();  // barrier 1

    {
        float off = zp;
        for (int ss = 0; ss < 4; ++ss)
            if (ss < zs) off += scratch[ss * 64 + zj];
#pragma unroll
        for (int t = 0; t < 16; ++t) zpart[t] += off;
    }

    // ---- stage 1: A = Q @ V^T (3-term hi/lo)
    floatx4 acc1[4];
#pragma unroll
    for (int nt = 0; nt < 4; ++nt) acc1[nt] = (floatx4){0.f, 0.f, 0.f, 0.f};
#pragma unroll
    for (int nt = 0; nt < 4; ++nt) {
#pragma unroll
        for (int ks = 0; ks < 2; ++ks) {
            short8 bH = *(const short8*)(VH + (nt * 16 + fm) * PS + ks * 32 + fq * 8);
            short8 bL = *(const short8*)(VL + (nt * 16 + fm) * PS + ks * 32 + fq * 8);
            acc1[nt] = __builtin_amdgcn_mfma_f32_16x16x32_bf16(qH[ks], bH, acc1[nt], 0, 0, 0);
            acc1[nt] = __builtin_amdgcn_mfma_f32_16x16x32_bf16(qH[ks], bL, acc1[nt], 0, 0, 0);
            acc1[nt] = __builtin_amdgcn_mfma_f32_16x16x32_bf16(qL[ks], bH, acc1[nt], 0, 0, 0);
        }
    }
    __syncthreads();  // barrier 2 (V reads + scratch reads done)

    // write tril(A) hi/lo (r-rotation for bank spread); Mt over V region
#pragma unroll
    for (int nt = 0; nt < 4; ++nt) {
        const int t = nt * 16 + fm;
#pragma unroll
        for (int r0 = 0; r0 < 4; ++r0) {
            const int r = (r0 + fm) & 3;
            const int i = 16 * w + fq * 4 + r;
            const float v = (t <= i) ? acc1[nt][r] : 0.f;
            unsigned short hh, ll;
            split2(v, hh, ll);
            AH[i * PS + t] = hh;
            AL[i * PS + t] = ll;
        }
    }
#pragma unroll
    for (int g = 0; g < 4; ++g) {
        float ma[4] = {mpre[g].x, mpre[g].y, mpre[g].z, mpre[g].w};
        union { unsigned short s[4]; uint2 v; } mh, ml;
#pragma unroll
        for (int e = 0; e < 4; ++e) split2(ma[e], mh.s[e], ml.s[e]);
        *(uint2*)(VH + lr * PS + lc0 + g * 4) = mh.v;
        *(uint2*)(VL + lr * PS + lc0 + g * 4) = ml.v;
    }
    __syncthreads();  // barrier 3

    // ---- stage 2: num = Q@Mt + A@KT (K=128)
    floatx4 acc2[4];
#pragma unroll
    for (int nt = 0; nt < 4; ++nt) acc2[nt] = (floatx4){0.f, 0.f, 0.f, 0.f};
    {
        short8 aAH[2], aAL[2];
#pragma unroll
        for (int ks = 0; ks < 2; ++ks) {
            aAH[ks] = *(const short8*)(AH + (16 * w + fm) * PS + ks * 32 + fq * 8);
            aAL[ks] = *(const short8*)(AL + (16 * w + fm) * PS + ks * 32 + fq * 8);
        }
#pragma unroll
        for (int nt = 0; nt < 4; ++nt) {
            const int rb = (nt * 16 + fm) * PS + fq * 8;
#pragma unroll
            for (int ks = 0; ks < 2; ++ks) {
                short8 bH = *(const short8*)(VH + rb + ks * 32);
                short8 bL = *(const short8*)(VL + rb + ks * 32);
                acc2[nt] = __builtin_amdgcn_mfma_f32_16x16x32_bf16(qH[ks], bH, acc2[nt], 0, 0, 0);
                acc2[nt] = __builtin_amdgcn_mfma_f32_16x16x32_bf16(qH[ks], bL, acc2[nt], 0, 0, 0);
                acc2[nt] = __builtin_amdgcn_mfma_f32_16x16x32_bf16(qL[ks], bH, acc2[nt], 0, 0, 0);
            }
#pragma unroll
            for (int ks = 0; ks < 2; ++ks) {
                short8 bH = *(const short8*)(KTH + rb + ks * 32);
                short8 bL = *(const short8*)(KTL + rb + ks * 32);
                acc2[nt] = __builtin_amdgcn_mfma_f32_16x16x32_bf16(aAH[ks], bH, acc2[nt], 0, 0, 0);
                acc2[nt] = __builtin_amdgcn_mfma_f32_16x16x32_bf16(aAH[ks], bL, acc2[nt], 0, 0, 0);
                acc2[nt] = __builtin_amdgcn_mfma_f32_16x16x32_bf16(aAL[ks], bH, acc2[nt], 0, 0, 0);
            }
        }
    }
    __syncthreads();  // barrier 4 (KT reads done)

    // write absolute Z over KT region, layout Zf[j][i], stride 67
#pragma unroll
    for (int t = 0; t < 16; ++t)
        Zf[zj * 67 + zs * 16 + t] = zpart[t];
    __syncthreads();  // barrier 5

    // epilogue
#pragma unroll
    for (int nt = 0; nt < 4; ++nt) {
        const int j = nt * 16 + fm;
#pragma unroll
        for (int r = 0; r < 4; ++r) {
            const int i = 16 * w + fq * 4 + r;
            const float q = Qs[i * 68 + j];
            const float z = Zf[j * 67 + i];
            const float denom = fmaf(q, z, EPSC);
            Outb[gbase + (size_t)i * DM + j] = f2bf(acc2[nt][r] / denom);
        }
    }
}

// ---------------------------------------------------------------------------
// Launch
// ---------------------------------------------------------------------------
extern "C" void kernel_launch(void* const* d_in, const int* in_sizes, int n_in,
                              void* d_out, int out_size, void* d_ws, size_t ws_size,
                              hipStream_t stream)
{
    (void)in_sizes; (void)n_in; (void)out_size; (void)ws_size;

    const float* queries = (const float*)d_in[0];
    const float* keys    = (const float*)d_in[1];
    const float* values  = (const float*)d_in[2];
    const float* Wq = (const float*)d_in[3];
    const float* bq = (const float*)d_in[4];
    const float* Wk = (const float*)d_in[5];
    const float* bk = (const float*)d_in[6];
    const float* Wv = (const float*)d_in[7];
    const float* bv = (const float*)d_in[8];
    const float* Wo = (const float*)d_in[9];
    const float* bo = (const float*)d_in[10];

    char* ws = (char*)d_ws;
    const size_t MB = 1u << 20;
    unsigned short* qb  = (unsigned short*)(ws);             // 16 MB
    unsigned short* kb  = (unsigned short*)(ws + 16 * MB);   // 16 MB
    unsigned short* vb  = (unsigned short*)(ws + 32 * MB);   // 16 MB
    unsigned short* Wqt = (unsigned short*)(ws + 48 * MB);
    unsigned short* Wkt = (unsigned short*)(ws + 50 * MB);
    unsigned short* Wvt = (unsigned short*)(ws + 52 * MB);
    unsigned short* Wot = (unsigned short*)(ws + 54 * MB);
    float* Qf = (float*)(ws + 56 * MB);                      // 32 MB
    float* Kc = (float*)(ws + 88 * MB);                      // 32 MB (KT-chunk layout)
    float* Vf = (float*)(ws + 120 * MB);                     // 32 MB
    float* Zc = (float*)(ws + 152 * MB);                     // 0.5 MB
    unsigned short* attnb = (unsigned short*)(ws);           // reuse qb
    float* Mst = (float*)(ws + 16 * MB);                     // reuse kb+vb

    const dim3 gblk(256);
    const dim3 gG(DM / 128, (BB * LL) / 128);

    convert3<<<dim3(3 * 4096), gblk, 0, stream>>>(queries, keys, values, qb, kb, vb);
    transpose4<<<dim3(16, 16, 4), gblk, 0, stream>>>(Wq, Wk, Wv, Wo, Wqt, Wkt, Wvt, Wot);

    gemm_mfma<<<gG, gblk, 0, stream>>>(qb, Wqt, bq, Qf, 1, 0);
    gemm_mfma<<<gG, gblk, 0, stream>>>(kb, Wkt, bk, Kc, 1, 1);  // KT-chunk layout
    gemm_mfma<<<gG, gblk, 0, stream>>>(vb, Wvt, bv, Vf, 0, 0);

    chunk_state<<<dim3(BB * HH * NC), gblk, 0, stream>>>(Kc, Vf, Mst, Zc);
    prefix_state<<<dim3(BB * HH * 16), gblk, 0, stream>>>(Mst, Zc);
    chunk_attn<<<dim3(BB * HH * NC), gblk, 0, stream>>>(Qf, Kc, Vf, Mst, Zc, attnb);

    gemm_mfma<<<gG, gblk, 0, stream>>>(attnb, Wot, bo, (float*)d_out, 0, 0);
}

// Round 6
// 326.108 us; speedup vs baseline: 3.4849x; 1.1325x over previous
//
#include <hip/hip_runtime.h>
#include <math.h>

// Problem constants
#define DM 1024      // d_model
#define LL 2048      // sequence length
#define BB 4         // batch
#define HH 16        // heads
#define HD 64        // head dim
#define CC 64        // chunk size
#define NC (LL / CC) // 32 chunks
#define EPSC 1e-6f
#define PS 72        // padded LDS stride (elements) for VALU-written 64-wide tiles

typedef __attribute__((ext_vector_type(8))) short short8;      // 8 bf16
typedef __attribute__((ext_vector_type(8))) _Float16 half8;    // 8 f16
typedef __attribute__((ext_vector_type(4))) float floatx4;     // MFMA acc

__device__ __forceinline__ float featf(float x) { return x > 0.f ? x + 1.f : __expf(x); }

// round-to-nearest-even f32 -> bf16 bits
__device__ __forceinline__ unsigned short f2bf(float f) {
    unsigned int u = __builtin_bit_cast(unsigned int, f);
    u = (u + 0x7FFFu + ((u >> 16) & 1u)) >> 16;
    return (unsigned short)u;
}

__device__ __forceinline__ void gload_lds16(const void* g, void* l) {
    __builtin_amdgcn_global_load_lds(
        (const __attribute__((address_space(1))) void*)g,
        (__attribute__((address_space(3))) void*)l,
        16, 0, 0);
}

// Stage a 64x64 2-byte-element tile (8 KB) global -> LDS, XOR-8 chunk swizzle
// baked into the SOURCE address. LDS: row*128B + slot*16B, slot = g ^ (row&7).
__device__ __forceinline__ void stage_tile(const void* gp_, int rowstride,
                                           char* lds_base, int tid) {
    const unsigned short* gp = (const unsigned short*)gp_;
#pragma unroll
    for (int m = 0; m < 2; ++m) {
        const int row = m * 32 + (tid >> 3);
        const int g = (tid & 7) ^ (row & 7);
        gload_lds16(gp + (size_t)row * rowstride + g * 8,
                    lds_base + m * 4096 + tid * 16);
    }
}
__device__ __forceinline__ half8 frag_ldh(const char* base, int row, int kc) {
    return *(const half8*)(base + row * 128 + (((kc) ^ (row & 7)) << 4));
}

// ---------------------------------------------------------------------------
// fused f32 -> bf16 convert for q,k,v inputs
// ---------------------------------------------------------------------------
__global__ __launch_bounds__(256) void convert3(
    const float* __restrict__ a, const float* __restrict__ b,
    const float* __restrict__ c, unsigned short* __restrict__ oa,
    unsigned short* __restrict__ ob, unsigned short* __restrict__ oc)
{
    const int blk = blockIdx.x;
    const int sel = blk >> 12;
    const float* src = (sel == 0) ? a : (sel == 1) ? b : c;
    unsigned short* dst = (sel == 0) ? oa : (sel == 1) ? ob : oc;
    const int i = (blk & 4095) * 256 + threadIdx.x;
    const float4 x = ((const float4*)src)[i * 2];
    const float4 y = ((const float4*)src)[i * 2 + 1];
    union { unsigned short s[8]; uint4 v; } o;
    o.s[0] = f2bf(x.x); o.s[1] = f2bf(x.y); o.s[2] = f2bf(x.z); o.s[3] = f2bf(x.w);
    o.s[4] = f2bf(y.x); o.s[5] = f2bf(y.y); o.s[6] = f2bf(y.z); o.s[7] = f2bf(y.w);
    ((uint4*)dst)[i] = o.v;
}

// ---------------------------------------------------------------------------
// fused weight transpose+convert: W [K][N] f32 -> Wt [N][K] bf16, 4 weights
// ---------------------------------------------------------------------------
__global__ __launch_bounds__(256) void transpose4(
    const float* __restrict__ W0, const float* __restrict__ W1,
    const float* __restrict__ W2, const float* __restrict__ W3,
    unsigned short* __restrict__ T0, unsigned short* __restrict__ T1,
    unsigned short* __restrict__ T2, unsigned short* __restrict__ T3)
{
    __shared__ float tile[64][65];
    const int sel = blockIdx.z;
    const float* W = (sel == 0) ? W0 : (sel == 1) ? W1 : (sel == 2) ? W2 : W3;
    unsigned short* Wt = (sel == 0) ? T0 : (sel == 1) ? T1 : (sel == 2) ? T2 : T3;
    const int r0 = blockIdx.y * 64, c0 = blockIdx.x * 64;
    const int tid = threadIdx.x;
#pragma unroll
    for (int e = 0; e < 16; ++e) {
        const int idx = e * 256 + tid;
        const int r = idx >> 6, c = idx & 63;
        tile[r][c] = W[(size_t)(r0 + r) * DM + c0 + c];
    }
    __syncthreads();
#pragma unroll
    for (int e = 0; e < 16; ++e) {
        const int idx = e * 256 + tid;
        const int co = idx >> 6, ro = idx & 63;
        Wt[(size_t)(c0 + co) * DM + r0 + ro] = f2bf(tile[ro][co]);
    }
}

// ---------------------------------------------------------------------------
// bf16 MFMA GEMM. mode 0: f32 rows -> Yf (final output).
// mode 1: f16 single plane, row-major -> Yh (Q,V projections).
// mode 2: f16 single plane, KT-chunk layout [blk][j][t] -> Yh (K projection).
// ---------------------------------------------------------------------------
__global__ __launch_bounds__(256) void gemm_mfma(
    const unsigned short* __restrict__ X,
    const unsigned short* __restrict__ Wt,
    const float* __restrict__ bias,
    float* __restrict__ Yf,
    _Float16* __restrict__ Yh,
    int act, int mode)
{
    __shared__ __align__(16) unsigned short As[128 * 32];
    __shared__ __align__(16) unsigned short Bs[128 * 32];

    const int tid = threadIdx.x;
    const int lane = tid & 63;
    const int w = tid >> 6;
    const int wr = w >> 1, wc = w & 1;
    const int fm = lane & 15;
    const int fq = lane >> 4;
    const int m0 = blockIdx.y * 128, n0 = blockIdx.x * 128;

    floatx4 acc[4][4];
#pragma unroll
    for (int i = 0; i < 4; ++i)
#pragma unroll
        for (int j = 0; j < 4; ++j) acc[i][j] = (floatx4){0.f, 0.f, 0.f, 0.f};

    const int row0 = tid >> 2;
    const int row1 = row0 + 64;
    const int slot0 = (tid & 3) ^ (row0 & 3);
    const int slot1 = (tid & 3) ^ (row1 & 3);
    const unsigned short* Xa = X + (size_t)(m0 + row0) * DM + slot0 * 8;
    const unsigned short* Xb = X + (size_t)(m0 + row1) * DM + slot1 * 8;
    const unsigned short* Wa = Wt + (size_t)(n0 + row0) * DM + slot0 * 8;
    const unsigned short* Wb = Wt + (size_t)(n0 + row1) * DM + slot1 * 8;

    const int fswz = ((fq ^ (fm & 3)) << 3);

    for (int k0 = 0; k0 < DM; k0 += 32) {
        gload_lds16(Xa + k0, As + (size_t)tid * 8);
        gload_lds16(Xb + k0, As + (size_t)(256 + tid) * 8);
        gload_lds16(Wa + k0, Bs + (size_t)tid * 8);
        gload_lds16(Wb + k0, Bs + (size_t)(256 + tid) * 8);
        __syncthreads();

        short8 af[4], bf[4];
#pragma unroll
        for (int mt = 0; mt < 4; ++mt)
            af[mt] = *(const short8*)(As + (wr * 64 + mt * 16 + fm) * 32 + fswz);
#pragma unroll
        for (int nt = 0; nt < 4; ++nt)
            bf[nt] = *(const short8*)(Bs + (wc * 64 + nt * 16 + fm) * 32 + fswz);
#pragma unroll
        for (int mt = 0; mt < 4; ++mt)
#pragma unroll
            for (int nt = 0; nt < 4; ++nt)
                acc[mt][nt] = __builtin_amdgcn_mfma_f32_16x16x32_bf16(
                    af[mt], bf[nt], acc[mt][nt], 0, 0, 0);
        __syncthreads();
    }

    if (mode == 0) {
#pragma unroll
        for (int nt = 0; nt < 4; ++nt) {
            const int col = n0 + wc * 64 + nt * 16 + fm;
            const float bv = bias[col];
#pragma unroll
            for (int mt = 0; mt < 4; ++mt) {
                const int rbase = m0 + wr * 64 + mt * 16 + fq * 4;
#pragma unroll
                for (int r = 0; r < 4; ++r) {
                    float v = acc[mt][nt][r] + bv;
                    if (act) v = featf(v);
                    Yf[(size_t)(rbase + r) * DM + col] = v;
                }
            }
        }
    } else if (mode == 1) {
#pragma unroll
        for (int nt = 0; nt < 4; ++nt) {
            const int col = n0 + wc * 64 + nt * 16 + fm;
            const float bv = bias[col];
#pragma unroll
            for (int mt = 0; mt < 4; ++mt) {
                const int rbase = m0 + wr * 64 + mt * 16 + fq * 4;
#pragma unroll
                for (int r = 0; r < 4; ++r) {
                    float v = acc[mt][nt][r] + bv;
                    if (act) v = featf(v);
                    Yh[(size_t)(rbase + r) * DM + col] = (_Float16)v;
                }
            }
        }
    } else {
        // KT-chunk layout [blk][j][t], blk = (b*16+h)*32 + chunk
        const int b = m0 >> 11;
        const int cch = ((m0 & 2047) >> 6) + wr;
        const int h = (n0 >> 6) + wc;
        _Float16* hb = Yh + ((size_t)((b * 16 + h) * 32 + cch)) * 4096;
#pragma unroll
        for (int nt = 0; nt < 4; ++nt) {
            const int j = nt * 16 + fm;
            const float bv = bias[n0 + wc * 64 + nt * 16 + fm];
#pragma unroll
            for (int mt = 0; mt < 4; ++mt) {
                float o[4];
#pragma unroll
                for (int r = 0; r < 4; ++r) {
                    float v = acc[mt][nt][r] + bv;
                    if (act) v = featf(v);
                    o[r] = v;
                }
                union { _Float16 h[4]; uint2 v; } pk;
#pragma unroll
                for (int r = 0; r < 4; ++r) pk.h[r] = (_Float16)o[r];
                *(uint2*)(hb + j * 64 + mt * 16 + fq * 4) = pk.v;
            }
        }
    }
}

// ===========================================================================
// chunk_state: Mc[j][dv] = sum_t K[t][j]*V[t][dv] (f16 plane out),
// Zc[j] = sum_t K[t][j] (f32). KTp is the f16 KT-chunk plane. LDS 18.4 KB.
// ===========================================================================
__global__ __launch_bounds__(256) void chunk_state(
    const _Float16* __restrict__ KTp, const _Float16* __restrict__ Vp,
    _Float16* __restrict__ Mc, float* __restrict__ Zc)
{
    __shared__ __align__(16) char smem[18432];
    // [0,8192) KT tile  [8192,17408) VT f16 padded  [17408,18432) scratch
    _Float16* VT = (_Float16*)(smem + 8192);
    float* scratch = (float*)(smem + 17408);

    const int blk = blockIdx.x;
    const int bh = blk / NC, c = blk % NC;
    const int b = bh / HH, h = bh % HH;
    const int tid = threadIdx.x;
    const int w = tid >> 6, lane = tid & 63;
    const int fm = lane & 15, fq = lane >> 4;
    const size_t gbase = ((size_t)(b * LL + c * CC)) * DM + h * HD;
    const _Float16* Kblk = KTp + (size_t)blk * 4096;

    stage_tile(Kblk, 64, smem, tid);

    const int lr = tid >> 2, lc0 = (tid & 3) * 16;
    // V rows (f16 plane) -> transposed VT, e-rotated scatter (2-way banks)
    {
        half8 v0 = *(const half8*)(Vp + gbase + (size_t)lr * DM + lc0);
        half8 v1 = *(const half8*)(Vp + gbase + (size_t)lr * DM + lc0 + 8);
        _Float16 va[16];
#pragma unroll
        for (int e = 0; e < 8; ++e) { va[e] = v0[e]; va[8 + e] = v1[e]; }
#pragma unroll
        for (int g = 0; g < 4; ++g)
#pragma unroll
            for (int e0 = 0; e0 < 4; ++e0) {
                const int e = g * 4 + ((e0 + tid) & 3);
                VT[(lc0 + e) * PS + lr] = va[e];
            }
    }
    // Z partials: thread (zs,zj) sums 16 t's of KT row zj (contiguous f16)
    {
        const int zj = tid & 63, zs = tid >> 6;
        half8 k0 = *(const half8*)(Kblk + zj * 64 + zs * 16);
        half8 k1 = *(const half8*)(Kblk + zj * 64 + zs * 16 + 8);
        float z = 0.f;
#pragma unroll
        for (int e = 0; e < 8; ++e) z += (float)k0[e] + (float)k1[e];
        scratch[zs * 64 + zj] = z;
    }
    __syncthreads();

    if (tid < 64) {
        Zc[(size_t)blk * 64 + tid] = scratch[tid] + scratch[64 + tid] +
                                     scratch[128 + tid] + scratch[192 + tid];
    }

    // MFMA f16: C[j][dv]; A = KT rows (swizzled tile), B = VT rows (padded)
    floatx4 acc[4];
#pragma unroll
    for (int nt = 0; nt < 4; ++nt) acc[nt] = (floatx4){0.f, 0.f, 0.f, 0.f};
    half8 aK[2];
#pragma unroll
    for (int ks = 0; ks < 2; ++ks)
        aK[ks] = frag_ldh(smem, 16 * w + fm, ks * 4 + fq);
#pragma unroll
    for (int nt = 0; nt < 4; ++nt) {
#pragma unroll
        for (int ks = 0; ks < 2; ++ks) {
            half8 bV = *(const half8*)(VT + (nt * 16 + fm) * PS + ks * 32 + fq * 8);
            acc[nt] = __builtin_amdgcn_mfma_f32_16x16x32_f16(aK[ks], bV, acc[nt], 0, 0, 0);
        }
    }
    _Float16* Mout = Mc + (size_t)blk * 4096;
#pragma unroll
    for (int nt = 0; nt < 4; ++nt) {
        const int dv = nt * 16 + fm;
#pragma unroll
        for (int r = 0; r < 4; ++r) {
            const int j = 16 * w + fq * 4 + r;
            Mout[j * 64 + dv] = (_Float16)acc[nt][r];
        }
    }
}

// ---------------------------------------------------------------------------
// exclusive prefix over chunks on the f16 Mc plane (f32 accumulator) + Z
// ---------------------------------------------------------------------------
__global__ __launch_bounds__(256) void prefix_state(
    _Float16* __restrict__ Mc, float* __restrict__ Zc)
{
    const int bh = blockIdx.x >> 4;
    const int slice = blockIdx.x & 15;
    const int off = slice * 256 + threadIdx.x;
    float run = 0.f;
    _Float16* p = Mc + (size_t)bh * NC * 4096 + off;
    for (int c = 0; c < NC; ++c) {
        const float v = (float)p[(size_t)c * 4096];
        p[(size_t)c * 4096] = (_Float16)run;
        run += v;
    }
    if (slice == 0 && threadIdx.x < 64) {
        float z = 0.f;
        float* zb = Zc + (size_t)bh * NC * 64 + threadIdx.x;
        for (int c = 0; c < NC; ++c) {
            const float v = zb[c * 64];
            zb[c * 64] = z;
            z += v;
        }
    }
}

// ===========================================================================
// chunk_attn v4 (all-f16): Q,V,KT,Mt tiles staged via global_load_lds into
// XOR-swizzled tiles; ONE barrier; A/Z/epilogue wave-local. LDS 50.3 KB
// -> 3 blk/CU. 24 MFMA/wave.
// ===========================================================================
#define ATT_Q  0
#define ATT_V  8192
#define ATT_K  16384
#define ATT_M  24576
#define ATT_A  32768   // 64 x PS f16 = 9216 B
#define ATT_Z  41984   // 64 x 65 f16 = 8320 B
__global__ __launch_bounds__(256) void chunk_attn(
    const _Float16* __restrict__ Qp, const _Float16* __restrict__ Vp,
    const _Float16* __restrict__ KTp, const _Float16* __restrict__ Mtp,
    const float* __restrict__ Zprev, unsigned short* __restrict__ Outb)
{
    __shared__ __align__(16) char smem[50304];
    _Float16* AT = (_Float16*)(smem + ATT_A);
    _Float16* Zf = (_Float16*)(smem + ATT_Z);

    const int blk = blockIdx.x;
    const int bh = blk / NC, c = blk % NC;
    const int b = bh / HH, h = bh % HH;
    const int tid = threadIdx.x;
    const int w = tid >> 6, lane = tid & 63;
    const int fm = lane & 15, fq = lane >> 4;
    const size_t gbase = ((size_t)(b * LL + c * CC)) * DM + h * HD;
    const _Float16* Kblk = KTp + (size_t)blk * 4096;

    // ---- phase 0: async staging (8 global_load_lds, zero VALU)
    stage_tile(Qp + gbase, DM, smem + ATT_Q, tid);
    stage_tile(Vp + gbase, DM, smem + ATT_V, tid);
    stage_tile(Kblk, 64, smem + ATT_K, tid);
    stage_tile(Mtp + (size_t)blk * 4096, 64, smem + ATT_M, tid);

    // Z: wave-local. Lane j of wave w computes z[i][j] for i in strip w.
    {
        const int j = lane;
        const _Float16* kr = Kblk + (size_t)j * 64;
        float run = Zprev[(size_t)blk * 64 + j];
        for (int s = 0; s < w; ++s) {   // wave-uniform bound
            half8 k0 = *(const half8*)(kr + s * 16);
            half8 k1 = *(const half8*)(kr + s * 16 + 8);
#pragma unroll
            for (int e = 0; e < 8; ++e) run += (float)k0[e] + (float)k1[e];
        }
        half8 k0 = *(const half8*)(kr + w * 16);
        half8 k1 = *(const half8*)(kr + w * 16 + 8);
        float zrow[16];
#pragma unroll
        for (int e = 0; e < 8; ++e) { run += (float)k0[e]; zrow[e] = run; }
#pragma unroll
        for (int e = 0; e < 8; ++e) { run += (float)k1[e]; zrow[8 + e] = run; }
#pragma unroll
        for (int t = 0; t < 16; ++t)
            Zf[(16 * w + t) * 65 + j] = (_Float16)zrow[t];
    }
    __syncthreads();  // the ONLY barrier (drains global_load_lds)

    // Q fragments (A-operand rows 16w+fm), reused by stage 1 and stage 2
    half8 qf[2];
#pragma unroll
    for (int ks = 0; ks < 2; ++ks)
        qf[ks] = frag_ldh(smem + ATT_Q, 16 * w + fm, ks * 4 + fq);

    // ---- stage 1: A = Q @ V^T
    floatx4 acc1[4];
#pragma unroll
    for (int nt = 0; nt < 4; ++nt) acc1[nt] = (floatx4){0.f, 0.f, 0.f, 0.f};
#pragma unroll
    for (int nt = 0; nt < 4; ++nt) {
#pragma unroll
        for (int ks = 0; ks < 2; ++ks) {
            half8 bV = frag_ldh(smem + ATT_V, nt * 16 + fm, ks * 4 + fq);
            acc1[nt] = __builtin_amdgcn_mfma_f32_16x16x32_f16(qf[ks], bV, acc1[nt], 0, 0, 0);
        }
    }

    // write tril(A) f16 (wave-local rows, padded stride, r-rotated)
#pragma unroll
    for (int nt = 0; nt < 4; ++nt) {
        const int t = nt * 16 + fm;
#pragma unroll
        for (int r0 = 0; r0 < 4; ++r0) {
            const int r = (r0 + fm) & 3;
            const int i = 16 * w + fq * 4 + r;
            AT[i * PS + t] = (_Float16)((t <= i) ? acc1[nt][r] : 0.f);
        }
    }

    // ---- stage 2: num = Q@Mt + A@KT  (no barrier: A rows are wave-local)
    floatx4 acc2[4];
#pragma unroll
    for (int nt = 0; nt < 4; ++nt) acc2[nt] = (floatx4){0.f, 0.f, 0.f, 0.f};
    {
        half8 aA[2];
#pragma unroll
        for (int ks = 0; ks < 2; ++ks)
            aA[ks] = *(const half8*)(AT + (16 * w + fm) * PS + ks * 32 + fq * 8);
#pragma unroll
        for (int nt = 0; nt < 4; ++nt) {
#pragma unroll
            for (int ks = 0; ks < 2; ++ks) {
                half8 bM = frag_ldh(smem + ATT_M, nt * 16 + fm, ks * 4 + fq);
                acc2[nt] = __builtin_amdgcn_mfma_f32_16x16x32_f16(qf[ks], bM, acc2[nt], 0, 0, 0);
            }
#pragma unroll
            for (int ks = 0; ks < 2; ++ks) {
                half8 bK = frag_ldh(smem + ATT_K, nt * 16 + fm, ks * 4 + fq);
                acc2[nt] = __builtin_amdgcn_mfma_f32_16x16x32_f16(aA[ks], bK, acc2[nt], 0, 0, 0);
            }
        }
    }

    // ---- epilogue (wave-local Zf strip + swizzled Q reads), out bf16
#pragma unroll
    for (int nt = 0; nt < 4; ++nt) {
        const int j = nt * 16 + fm;
#pragma unroll
        for (int r = 0; r < 4; ++r) {
            const int i = 16 * w + fq * 4 + r;
            const int qoff = i * 128 + (((j >> 3) ^ (i & 7)) << 4) + (j & 7) * 2;
            const float q = (float)(*(const _Float16*)(smem + ATT_Q + qoff));
            const float z = (float)Zf[i * 65 + j];
            const float denom = fmaf(q, z, EPSC);
            Outb[gbase + (size_t)i * DM + j] = f2bf(acc2[nt][r] * __builtin_amdgcn_rcpf(denom));
        }
    }
}

// ---------------------------------------------------------------------------
// Launch.  Workspace map (byte offsets, NO overlaps):
//   [  0, 16) qb   bf16 8.4M elems = 16 MB     [ 16, 32) kb     16 MB
//   [ 32, 48) vb   16 MB                       [ 48, 56) Wt x4   8 MB
//   [ 56, 72) Qh   f16 8.4M = 16 MB            [ 72, 88) Vh     16 MB
//   [ 88,104) KTp  f16 16 MB                   [104,120) Mc f16 16 MB
//   [120,121) Zc   f32 0.5 MB                  [128,144) attnb  16 MB
// ---------------------------------------------------------------------------
extern "C" void kernel_launch(void* const* d_in, const int* in_sizes, int n_in,
                              void* d_out, int out_size, void* d_ws, size_t ws_size,
                              hipStream_t stream)
{
    (void)in_sizes; (void)n_in; (void)out_size; (void)ws_size;

    const float* queries = (const float*)d_in[0];
    const float* keys    = (const float*)d_in[1];
    const float* values  = (const float*)d_in[2];
    const float* Wq = (const float*)d_in[3];
    const float* bq = (const float*)d_in[4];
    const float* Wk = (const float*)d_in[5];
    const float* bk = (const float*)d_in[6];
    const float* Wv = (const float*)d_in[7];
    const float* bv = (const float*)d_in[8];
    const float* Wo = (const float*)d_in[9];
    const float* bo = (const float*)d_in[10];

    char* ws = (char*)d_ws;
    const size_t MB = 1u << 20;
    unsigned short* qb  = (unsigned short*)(ws);
    unsigned short* kb  = (unsigned short*)(ws + 16 * MB);
    unsigned short* vb  = (unsigned short*)(ws + 32 * MB);
    unsigned short* Wqt = (unsigned short*)(ws + 48 * MB);
    unsigned short* Wkt = (unsigned short*)(ws + 50 * MB);
    unsigned short* Wvt = (unsigned short*)(ws + 52 * MB);
    unsigned short* Wot = (unsigned short*)(ws + 54 * MB);
    _Float16* Qh  = (_Float16*)(ws + 56 * MB);
    _Float16* Vh  = (_Float16*)(ws + 72 * MB);
    _Float16* KTp = (_Float16*)(ws + 88 * MB);
    _Float16* Mc  = (_Float16*)(ws + 104 * MB);
    float* Zc     = (float*)(ws + 120 * MB);
    unsigned short* attnb = (unsigned short*)(ws + 128 * MB);

    const dim3 gblk(256);
    const dim3 gG(DM / 128, (BB * LL) / 128);

    convert3<<<dim3(3 * 4096), gblk, 0, stream>>>(queries, keys, values, qb, kb, vb);
    transpose4<<<dim3(16, 16, 4), gblk, 0, stream>>>(Wq, Wk, Wv, Wo, Wqt, Wkt, Wvt, Wot);

    gemm_mfma<<<gG, gblk, 0, stream>>>(qb, Wqt, bq, nullptr, Qh, 1, 1);
    gemm_mfma<<<gG, gblk, 0, stream>>>(kb, Wkt, bk, nullptr, KTp, 1, 2);
    gemm_mfma<<<gG, gblk, 0, stream>>>(vb, Wvt, bv, nullptr, Vh, 0, 1);

    chunk_state<<<dim3(BB * HH * NC), gblk, 0, stream>>>(KTp, Vh, Mc, Zc);
    prefix_state<<<dim3(BB * HH * 16), gblk, 0, stream>>>(Mc, Zc);
    chunk_attn<<<dim3(BB * HH * NC), gblk, 0, stream>>>(Qh, Vh, KTp, Mc, Zc, attnb);

    gemm_mfma<<<gG, gblk, 0, stream>>>(attnb, Wot, bo, (float*)d_out, nullptr, 0, 0);
}